// Round 1
// baseline (559.799 us; speedup 1.0000x reference)
//
#include <hip/hip_runtime.h>
#include <math.h>

#define HID 1024
#define NH  16
#define HD  64
#define NB  4
#define SL  2048
#define MROWS (NB * SL)   // 8192

typedef __attribute__((ext_vector_type(8))) short short8;
typedef __attribute__((ext_vector_type(4))) float f32x4;
typedef unsigned short ushort_t;
typedef unsigned int uint_t;

// fp32 -> bf16 bits, round-to-nearest-even
__device__ __forceinline__ uint_t f2bf(float x) {
    union { float f; uint_t u; } a; a.f = x;
    return (a.u + 0x7fffu + ((a.u >> 16) & 1u)) >> 16;
}

// async global->LDS, 16B per lane; LDS dest = wave-uniform base + lane*16
__device__ __forceinline__ void load_lds16(const void* g, void* l) {
    __builtin_amdgcn_global_load_lds(
        (const __attribute__((address_space(1))) void*)g,
        (__attribute__((address_space(3))) void*)l, 16, 0, 0);
}

// ---------------------------------------------------------------------------
// GEMM core: C(128x128) = A @ B^T, bf16, BK=64 (16 k-iters, 32 MFMA/wave/iter).
// LDS rows are 128 B = exactly 32 banks (row drops out of bank equation);
// chunks XOR-swizzled with r&7 (== c&7 at read) -> fragment b128 reads spread
// evenly over the 8 bank-groups.
// ---------------------------------------------------------------------------
__device__ __forceinline__ void gemm_core_bk64(
    const ushort_t* __restrict__ A, const ushort_t* __restrict__ B,
    const int m0, const int n0, ushort_t* As, ushort_t* Bs, f32x4 (&acc)[4][4])
{
    const int tid = threadIdx.x;
    const int w = tid >> 6, lane = tid & 63;
    const int wm = (w & 1) << 6, wn = (w >> 1) << 6;
    const int c = lane & 15, quad = lane >> 4;

    for (int k0 = 0; k0 < HID; k0 += 64) {
        __syncthreads();
        #pragma unroll
        for (int rd = 0; rd < 4; ++rd) {
            const int g = rd * 4 + w;            // wave-uniform group 0..15
            const int idx = g * 64 + lane;       // 16B-chunk id, 0..1023
            const int r = idx >> 3, sc = idx & 7;
            const int dc = sc ^ (r & 7);         // fetch permuted chunk
            load_lds16(&A[(size_t)(m0 + r) * HID + k0 + dc * 8], As + g * 512);
            load_lds16(&B[(size_t)(n0 + r) * HID + k0 + dc * 8], Bs + g * 512);
        }
        __syncthreads();

        #pragma unroll
        for (int ks = 0; ks < 2; ++ks) {
            short8 af[4], bf[4];
            #pragma unroll
            for (int i = 0; i < 4; ++i) {
                const int ra = wm + i * 16 + c;
                const int rb = wn + i * 16 + c;
                af[i] = *(const short8*)
                    &As[ra * 64 + ((((ks << 2) + quad) ^ (c & 7)) << 3)];
                bf[i] = *(const short8*)
                    &Bs[rb * 64 + ((((ks << 2) + quad) ^ (c & 7)) << 3)];
            }
            #pragma unroll
            for (int i = 0; i < 4; ++i)
                #pragma unroll
                for (int j = 0; j < 4; ++j)
                    acc[i][j] = __builtin_amdgcn_mfma_f32_16x16x32_bf16(
                        af[i], bf[j], acc[i][j], 0, 0, 0);
        }
    }
}

// ---------------------------------------------------------------------------
// fp32 -> bf16 conversion: 12 segments of 1M elems (x = 8 segs, 4 weights)
// ---------------------------------------------------------------------------
__global__ __launch_bounds__(256) void cvt_bf16_kernel(
    const float* __restrict__ x,
    const float* __restrict__ wq, const float* __restrict__ wk,
    const float* __restrict__ wv, const float* __restrict__ wo,
    ushort_t* __restrict__ xb, ushort_t* __restrict__ wqb,
    ushort_t* __restrict__ wkb, ushort_t* __restrict__ wvb,
    ushort_t* __restrict__ wob)
{
    const int seg = blockIdx.y;
    const float* src; ushort_t* dst;
    if (seg < 8)       { src = x + (size_t)seg * 1048576; dst = xb + (size_t)seg * 1048576; }
    else if (seg == 8) { src = wq; dst = wqb; }
    else if (seg == 9) { src = wk; dst = wkb; }
    else if (seg == 10){ src = wv; dst = wvb; }
    else               { src = wo; dst = wob; }
    const int i = (blockIdx.x * 256 + threadIdx.x) * 8;
    const float4 a = *(const float4*)&src[i];
    const float4 b = *(const float4*)&src[i + 4];
    uint4 o;
    o.x = f2bf(a.x) | (f2bf(a.y) << 16);
    o.y = f2bf(a.z) | (f2bf(a.w) << 16);
    o.z = f2bf(b.x) | (f2bf(b.y) << 16);
    o.w = f2bf(b.z) | (f2bf(b.w) << 16);
    *(uint4*)&dst[i] = o;
}

// ---------------------------------------------------------------------------
// QKV projection. grid (8 n-tiles, 64 m-tiles, 3 weights); 128x128 tile.
// Q pre-scaled by 0.125*log2(e); K as (B,H,S,D); V^T as (B,H,D,S).
// ---------------------------------------------------------------------------
__global__ __launch_bounds__(256) void qkv_mfma_kernel(
    const ushort_t* __restrict__ xb,
    const ushort_t* __restrict__ wqb, const ushort_t* __restrict__ wkb,
    const ushort_t* __restrict__ wvb,
    const float* __restrict__ bq, const float* __restrict__ bk,
    const float* __restrict__ bv,
    ushort_t* __restrict__ qo, ushort_t* __restrict__ ko,
    ushort_t* __restrict__ vo)
{
    __shared__ __align__(16) ushort_t As[128 * 64];   // 16 KB
    __shared__ __align__(16) ushort_t Bs[128 * 64];   // 16 KB

    const int wsel = blockIdx.z;
    const ushort_t* W    = (wsel == 0) ? wqb : (wsel == 1) ? wkb : wvb;
    const float*    bias = (wsel == 0) ? bq  : (wsel == 1) ? bk  : bv;
    const int m0 = blockIdx.y * 128, n0 = blockIdx.x * 128;

    f32x4 acc[4][4];
    const f32x4 zero = {0.f, 0.f, 0.f, 0.f};
    #pragma unroll
    for (int i = 0; i < 4; ++i)
        #pragma unroll
        for (int j = 0; j < 4; ++j) acc[i][j] = zero;

    gemm_core_bk64(xb, W, m0, n0, As, Bs, acc);

    const int tid = threadIdx.x;
    const int w = tid >> 6, lane = tid & 63;
    const int wm = (w & 1) << 6, wn = (w >> 1) << 6;
    const int c = lane & 15, quad = lane >> 4;
    // 0.125 (1/sqrt(64)) * log2(e): scores land in log2 domain
    const float qscale = (wsel == 0) ? 0.18033688f : 1.0f;

    #pragma unroll
    for (int j = 0; j < 4; ++j) {
        const int n_g = n0 + wn + j * 16 + c;
        const float bj = bias[n_g];
        const int h = n_g >> 6, d = n_g & 63;
        #pragma unroll
        for (int i = 0; i < 4; ++i) {
            const int mbase = m0 + wm + i * 16 + quad * 4;
            const int b = mbase >> 11;
            const int sbase = mbase & (SL - 1);
            if (wsel == 2) {
                ushort4 pk;
                pk.x = (ushort_t)f2bf(acc[i][j][0] + bj);
                pk.y = (ushort_t)f2bf(acc[i][j][1] + bj);
                pk.z = (ushort_t)f2bf(acc[i][j][2] + bj);
                pk.w = (ushort_t)f2bf(acc[i][j][3] + bj);
                *(ushort4*)&vo[(((size_t)(b * NH + h) * HD) + d) * SL + sbase] = pk;
            } else {
                ushort_t* dst = (wsel == 0) ? qo : ko;
                #pragma unroll
                for (int reg = 0; reg < 4; ++reg) {
                    const float v = (acc[i][j][reg] + bj) * qscale;
                    dst[(((size_t)(b * NH + h) * SL) + sbase + reg) * HD + d] =
                        (ushort_t)f2bf(v);
                }
            }
        }
    }
}

// ---------------------------------------------------------------------------
// MFMA flash attention, fixed-base softmax, 128-row q-tiles, 32 rows/wave.
//
// v2 changes (latency-bound per rocprof: Mfma 30 / VALU 47 / HBM 20 / occ 35):
//  * T14 async-STAGE split: next kt's K/V tiles are loaded into REGISTERS
//    right after the compute-entry barrier (plain global loads stay
//    outstanding through the whole compute phase -- no intervening
//    __syncthreads to drain vmcnt), then ds_write'd to LDS after the next
//    loop-top barrier. Removes the per-iteration global->LDS latency that
//    the old  barrier; global_load_lds; barrier(vmcnt 0)  structure
//    serialized against compute.
//  * Ps pad-stride 72 -> XOR-swizzled stride 64: element (row,col) lives at
//    row*64 + ((col>>3)^(row&7))*8 + (col&7).  Both writer (rows quad*4+reg)
//    and reader (rows +c) index the same key, and reads spread over all 8
//    16B bank-groups.  LDS total drops 34 KB -> exactly 32 KB => 5 blocks/CU
//    (was 4), occupancy cap 50% -> 62.5%.
//  * __launch_bounds__(256, 5): 5 waves/SIMD => reg cap 102; kernel needs
//    ~80 (60 before + 16 prefetch regs), so no spill expected.
// ---------------------------------------------------------------------------
__global__ __launch_bounds__(256, 5) void attn_mfma_kernel(
    const ushort_t* __restrict__ q, const ushort_t* __restrict__ k,
    const ushort_t* __restrict__ vt, const int* __restrict__ mask,
    ushort_t* __restrict__ ao)
{
    __shared__ __align__(16) ushort_t Ks[64 * 64];    // 8 KB
    __shared__ __align__(16) ushort_t Vs[64 * 64];    // 8 KB
    __shared__ __align__(16) ushort_t Ps[128 * 64];   // 16 KB (swizzled)

    const int qt = blockIdx.x;    // 0..15
    const int bh = blockIdx.y;
    const int b = bh >> 4, h = bh & 15;
    const int tid = threadIdx.x;
    const int w = tid >> 6, lane = tid & 63;
    const int c = lane & 15, quad = lane >> 4;

    const ushort_t* qp = q  + (size_t)bh * SL * HD + (size_t)qt * 128 * HD;
    const ushort_t* kp = k  + (size_t)bh * SL * HD;
    const ushort_t* vp = vt + (size_t)bh * HD * SL;

    short8 qf[2][2];
    #pragma unroll
    for (int mi = 0; mi < 2; ++mi)
        #pragma unroll
        for (int ks = 0; ks < 2; ++ks)
            qf[mi][ks] = *(const short8*)&qp[(size_t)(w * 32 + mi * 16 + c) * HD
                                             + ks * 32 + quad * 8];

    float l_s[2][4] = {};
    f32x4 oa[2][4];
    const f32x4 zero = {0.f, 0.f, 0.f, 0.f};
    #pragma unroll
    for (int mi = 0; mi < 2; ++mi)
        #pragma unroll
        for (int ni = 0; ni < 4; ++ni) oa[mi][ni] = zero;

    // per-thread staging geometry: 2 chunks each of K and V per iteration.
    // chunk t = (rd*4+w)*64+lane covers row r = t>>3, col-chunk sc = t&7.
    // LDS slot s holds row s>>3, content chunk (s&7)^key(row) -- same layout
    // the old pre-swizzled global_load_lds produced, so reads are unchanged.
    uint4 kr[2], vr[2];
    #pragma unroll
    for (int rd = 0; rd < 2; ++rd) {
        const int t = (rd * 4 + w) * 64 + lane;
        const int r = t >> 3, sc = t & 7;
        kr[rd] = *(const uint4*)&kp[(size_t)r * HD + sc * 8];
        vr[rd] = *(const uint4*)&vp[(size_t)r * SL + sc * 8];
    }

    for (int kt = 0; kt < SL / 64; ++kt) {
        __syncthreads();          // prev compute done; drains prefetch vmcnt
        // write prefetched tile: K keyed (r>>2)&7 (QK^T reads row 4c+ni),
        // V keyed r&7 (PV reads row ni*16+c)
        #pragma unroll
        for (int rd = 0; rd < 2; ++rd) {
            const int t = (rd * 4 + w) * 64 + lane;
            const int r = t >> 3, sc = t & 7;
            *(uint4*)&Ks[(r * 8 + (sc ^ ((r >> 2) & 7))) * 8] = kr[rd];
            *(uint4*)&Vs[(r * 8 + (sc ^ (r & 7))) * 8] = vr[rd];
        }
        __syncthreads();          // writes visible to all waves

        // issue next tile's loads now -- they stay in flight through the
        // whole compute phase (next drain is the next loop-top barrier)
        if (kt + 1 < SL / 64) {
            #pragma unroll
            for (int rd = 0; rd < 2; ++rd) {
                const int t = (rd * 4 + w) * 64 + lane;
                const int r = t >> 3, sc = t & 7;
                kr[rd] = *(const uint4*)&kp[(size_t)((kt + 1) * 64 + r) * HD + sc * 8];
                vr[rd] = *(const uint4*)&vp[(size_t)r * SL + (kt + 1) * 64 + sc * 8];
            }
        }

        // S = Q @ K^T, log2 domain. Column c of tile ni = key 4c+ni.
        f32x4 sf[2][4];
        #pragma unroll
        for (int mi = 0; mi < 2; ++mi)
            #pragma unroll
            for (int ni = 0; ni < 4; ++ni) sf[mi][ni] = zero;
        #pragma unroll
        for (int ni = 0; ni < 4; ++ni) {
            const int krow = 4 * c + ni;
            #pragma unroll
            for (int ks = 0; ks < 2; ++ks) {
                const short8 kf = *(const short8*)
                    &Ks[krow * 64 + (((ks * 4 + quad) ^ (c & 7)) << 3)];
                #pragma unroll
                for (int mi = 0; mi < 2; ++mi)
                    sf[mi][ni] = __builtin_amdgcn_mfma_f32_16x16x32_bf16(
                        qf[mi][ks], kf, sf[mi][ni], 0, 0, 0);
            }
        }

        const int4 mzv = *(const int4*)&mask[b * SL + kt * 64 + 4 * c];
        const int mz[4] = {mzv.x, mzv.y, mzv.z, mzv.w};

        #pragma unroll
        for (int mi = 0; mi < 2; ++mi) {
            #pragma unroll
            for (int reg = 0; reg < 4; ++reg) {
                float p[4];
                #pragma unroll
                for (int ni = 0; ni < 4; ++ni) {
                    float pv = __builtin_amdgcn_exp2f(sf[mi][ni][reg]);
                    p[ni] = (mz[ni] == 0) ? 0.f : pv;
                }
                l_s[mi][reg] += (p[0] + p[1]) + (p[2] + p[3]);
                union { float f; uint_t u; } u0, u1, u2, u3;
                u0.f = p[0]; u1.f = p[1]; u2.f = p[2]; u3.f = p[3];
                uint2 pk;
                pk.x = __builtin_amdgcn_perm(u1.u, u0.u, 0x07060302u);
                pk.y = __builtin_amdgcn_perm(u3.u, u2.u, 0x07060302u);
                // P row quad*4+reg, cols 4c..4c+3 -> chunk c>>1, half c&1
                const int prow = w * 32 + mi * 16 + quad * 4 + reg;
                *(uint2*)&Ps[prow * 64 + (((c >> 1) ^ (prow & 7)) * 8)
                             + ((c & 1) * 4)] = pk;
            }
        }
        // wave-local LDS round-trip: no barrier needed

        short8 pf[2][2];
        #pragma unroll
        for (int mi = 0; mi < 2; ++mi)
            #pragma unroll
            for (int ks = 0; ks < 2; ++ks) {
                const int prow = w * 32 + mi * 16 + c;
                pf[mi][ks] = *(const short8*)
                    &Ps[prow * 64 + (((ks * 4 + quad) ^ (prow & 7)) << 3)];
            }
        #pragma unroll
        for (int ni = 0; ni < 4; ++ni) {
            const int n = ni * 16 + c;
            #pragma unroll
            for (int ks = 0; ks < 2; ++ks) {
                const short8 vf = *(const short8*)
                    &Vs[n * 64 + (((ks * 4 + quad) ^ (c & 7)) << 3)];
                #pragma unroll
                for (int mi = 0; mi < 2; ++mi)
                    oa[mi][ni] = __builtin_amdgcn_mfma_f32_16x16x32_bf16(
                        pf[mi][ks], vf, oa[mi][ni], 0, 0, 0);
            }
        }
    }

    #pragma unroll
    for (int mi = 0; mi < 2; ++mi) {
        #pragma unroll
        for (int reg = 0; reg < 4; ++reg) {
            float l = l_s[mi][reg];
            #pragma unroll
            for (int off = 1; off < 16; off <<= 1)
                l += __shfl_xor(l, off, 64);
            const float inv = 1.f / l;
            const int s_g = qt * 128 + w * 32 + mi * 16 + quad * 4 + reg;
            #pragma unroll
            for (int ni = 0; ni < 4; ++ni) {
                const int d = ni * 16 + c;
                ao[((size_t)(b * SL + s_g)) * HID + h * HD + d] =
                    (ushort_t)f2bf(oa[mi][ni][reg] * inv);
            }
        }
    }
}

// ---------------------------------------------------------------------------
// Output projection: out(fp32) = ao_bf @ Wo^T + bo. grid (8, 64).
// ---------------------------------------------------------------------------
__global__ __launch_bounds__(256) void out_mfma_kernel(
    const ushort_t* __restrict__ aob, const ushort_t* __restrict__ wob,
    const float* __restrict__ bo, float* __restrict__ out)
{
    __shared__ __align__(16) ushort_t As[128 * 64];
    __shared__ __align__(16) ushort_t Bs[128 * 64];

    const int m0 = blockIdx.y * 128, n0 = blockIdx.x * 128;

    f32x4 acc[4][4];
    const f32x4 zero = {0.f, 0.f, 0.f, 0.f};
    #pragma unroll
    for (int i = 0; i < 4; ++i)
        #pragma unroll
        for (int j = 0; j < 4; ++j) acc[i][j] = zero;

    gemm_core_bk64(aob, wob, m0, n0, As, Bs, acc);

    const int tid = threadIdx.x;
    const int w = tid >> 6, lane = tid & 63;
    const int wm = (w & 1) << 6, wn = (w >> 1) << 6;
    const int c = lane & 15, quad = lane >> 4;

    #pragma unroll
    for (int j = 0; j < 4; ++j) {
        const int n_g = n0 + wn + j * 16 + c;
        const float bj = bo[n_g];
        #pragma unroll
        for (int i = 0; i < 4; ++i) {
            const int mbase = m0 + wm + i * 16 + quad * 4;
            #pragma unroll
            for (int reg = 0; reg < 4; ++reg)
                out[(size_t)(mbase + reg) * HID + n_g] = acc[i][j][reg] + bj;
        }
    }
}

extern "C" void kernel_launch(void* const* d_in, const int* in_sizes, int n_in,
                              void* d_out, int out_size, void* d_ws, size_t ws_size,
                              hipStream_t stream)
{
    const float* x    = (const float*)d_in[0];
    const int*   mask = (const int*)d_in[1];
    const float* Wq   = (const float*)d_in[2];
    const float* bq   = (const float*)d_in[3];
    const float* Wk   = (const float*)d_in[4];
    const float* bk   = (const float*)d_in[5];
    const float* Wv   = (const float*)d_in[6];
    const float* bv   = (const float*)d_in[7];
    const float* Wo   = (const float*)d_in[8];
    const float* bo   = (const float*)d_in[9];
    float* out = (float*)d_out;

    ushort_t* p = (ushort_t*)d_ws;
    ushort_t* xb  = p; p += (size_t)MROWS * HID;
    ushort_t* wqb = p; p += (size_t)HID * HID;
    ushort_t* wkb = p; p += (size_t)HID * HID;
    ushort_t* wvb = p; p += (size_t)HID * HID;
    ushort_t* wob = p; p += (size_t)HID * HID;
    ushort_t* qb  = p; p += (size_t)MROWS * HID;
    ushort_t* kb  = p; p += (size_t)MROWS * HID;
    ushort_t* vtb = p; p += (size_t)MROWS * HID;
    ushort_t* aob = p; p += (size_t)MROWS * HID;

    cvt_bf16_kernel<<<dim3(512, 12), 256, 0, stream>>>(
        x, Wq, Wk, Wv, Wo, xb, wqb, wkb, wvb, wob);
    qkv_mfma_kernel<<<dim3(8, 64, 3), 256, 0, stream>>>(
        xb, wqb, wkb, wvb, bq, bk, bv, qb, kb, vtb);
    attn_mfma_kernel<<<dim3(16, 64), 256, 0, stream>>>(
        qb, kb, vtb, mask, aob);
    out_mfma_kernel<<<dim3(8, 64), 256, 0, stream>>>(
        aob, wob, bo, out);
}

// Round 2
// 467.297 us; speedup vs baseline: 1.1980x; 1.1980x over previous
//
#include <hip/hip_runtime.h>
#include <math.h>

#define HID 1024
#define NH  16
#define HD  64
#define NB  4
#define SL  2048
#define MROWS (NB * SL)   // 8192

typedef __attribute__((ext_vector_type(8))) short short8;
typedef __attribute__((ext_vector_type(4))) float f32x4;
typedef unsigned short ushort_t;
typedef unsigned int uint_t;

// fp32 -> bf16 bits, round-to-nearest-even
__device__ __forceinline__ uint_t f2bf(float x) {
    union { float f; uint_t u; } a; a.f = x;
    return (a.u + 0x7fffu + ((a.u >> 16) & 1u)) >> 16;
}

// async global->LDS, 16B per lane; LDS dest = wave-uniform base + lane*16
__device__ __forceinline__ void load_lds16(const void* g, void* l) {
    __builtin_amdgcn_global_load_lds(
        (const __attribute__((address_space(1))) void*)g,
        (__attribute__((address_space(3))) void*)l, 16, 0, 0);
}

// ---------------------------------------------------------------------------
// GEMM core: C(128x128) = A @ B^T, bf16, BK=64 (16 k-iters, 32 MFMA/wave/iter).
// LDS rows are 128 B = exactly 32 banks (row drops out of bank equation);
// chunks XOR-swizzled with r&7 (== c&7 at read) -> fragment b128 reads spread
// evenly over the 8 bank-groups.
// ---------------------------------------------------------------------------
__device__ __forceinline__ void gemm_core_bk64(
    const ushort_t* __restrict__ A, const ushort_t* __restrict__ B,
    const int m0, const int n0, ushort_t* As, ushort_t* Bs, f32x4 (&acc)[4][4])
{
    const int tid = threadIdx.x;
    const int w = tid >> 6, lane = tid & 63;
    const int wm = (w & 1) << 6, wn = (w >> 1) << 6;
    const int c = lane & 15, quad = lane >> 4;

    for (int k0 = 0; k0 < HID; k0 += 64) {
        __syncthreads();
        #pragma unroll
        for (int rd = 0; rd < 4; ++rd) {
            const int g = rd * 4 + w;            // wave-uniform group 0..15
            const int idx = g * 64 + lane;       // 16B-chunk id, 0..1023
            const int r = idx >> 3, sc = idx & 7;
            const int dc = sc ^ (r & 7);         // fetch permuted chunk
            load_lds16(&A[(size_t)(m0 + r) * HID + k0 + dc * 8], As + g * 512);
            load_lds16(&B[(size_t)(n0 + r) * HID + k0 + dc * 8], Bs + g * 512);
        }
        __syncthreads();

        #pragma unroll
        for (int ks = 0; ks < 2; ++ks) {
            short8 af[4], bf[4];
            #pragma unroll
            for (int i = 0; i < 4; ++i) {
                const int ra = wm + i * 16 + c;
                const int rb = wn + i * 16 + c;
                af[i] = *(const short8*)
                    &As[ra * 64 + ((((ks << 2) + quad) ^ (c & 7)) << 3)];
                bf[i] = *(const short8*)
                    &Bs[rb * 64 + ((((ks << 2) + quad) ^ (c & 7)) << 3)];
            }
            #pragma unroll
            for (int i = 0; i < 4; ++i)
                #pragma unroll
                for (int j = 0; j < 4; ++j)
                    acc[i][j] = __builtin_amdgcn_mfma_f32_16x16x32_bf16(
                        af[i], bf[j], acc[i][j], 0, 0, 0);
        }
    }
}

// ---------------------------------------------------------------------------
// fp32 -> bf16 conversion: 12 segments of 1M elems (x = 8 segs, 4 weights)
// ---------------------------------------------------------------------------
__global__ __launch_bounds__(256) void cvt_bf16_kernel(
    const float* __restrict__ x,
    const float* __restrict__ wq, const float* __restrict__ wk,
    const float* __restrict__ wv, const float* __restrict__ wo,
    ushort_t* __restrict__ xb, ushort_t* __restrict__ wqb,
    ushort_t* __restrict__ wkb, ushort_t* __restrict__ wvb,
    ushort_t* __restrict__ wob)
{
    const int seg = blockIdx.y;
    const float* src; ushort_t* dst;
    if (seg < 8)       { src = x + (size_t)seg * 1048576; dst = xb + (size_t)seg * 1048576; }
    else if (seg == 8) { src = wq; dst = wqb; }
    else if (seg == 9) { src = wk; dst = wkb; }
    else if (seg == 10){ src = wv; dst = wvb; }
    else               { src = wo; dst = wob; }
    const int i = (blockIdx.x * 256 + threadIdx.x) * 8;
    const float4 a = *(const float4*)&src[i];
    const float4 b = *(const float4*)&src[i + 4];
    uint4 o;
    o.x = f2bf(a.x) | (f2bf(a.y) << 16);
    o.y = f2bf(a.z) | (f2bf(a.w) << 16);
    o.z = f2bf(b.x) | (f2bf(b.y) << 16);
    o.w = f2bf(b.z) | (f2bf(b.w) << 16);
    *(uint4*)&dst[i] = o;
}

// ---------------------------------------------------------------------------
// QKV projection. grid (8 n-tiles, 64 m-tiles, 3 weights); 128x128 tile.
// Q pre-scaled by 0.125*log2(e); K as (B,H,S,D); V^T as (B,H,D,S).
// ---------------------------------------------------------------------------
__global__ __launch_bounds__(256) void qkv_mfma_kernel(
    const ushort_t* __restrict__ xb,
    const ushort_t* __restrict__ wqb, const ushort_t* __restrict__ wkb,
    const ushort_t* __restrict__ wvb,
    const float* __restrict__ bq, const float* __restrict__ bk,
    const float* __restrict__ bv,
    ushort_t* __restrict__ qo, ushort_t* __restrict__ ko,
    ushort_t* __restrict__ vo)
{
    __shared__ __align__(16) ushort_t As[128 * 64];   // 16 KB
    __shared__ __align__(16) ushort_t Bs[128 * 64];   // 16 KB

    const int wsel = blockIdx.z;
    const ushort_t* W    = (wsel == 0) ? wqb : (wsel == 1) ? wkb : wvb;
    const float*    bias = (wsel == 0) ? bq  : (wsel == 1) ? bk  : bv;
    const int m0 = blockIdx.y * 128, n0 = blockIdx.x * 128;

    f32x4 acc[4][4];
    const f32x4 zero = {0.f, 0.f, 0.f, 0.f};
    #pragma unroll
    for (int i = 0; i < 4; ++i)
        #pragma unroll
        for (int j = 0; j < 4; ++j) acc[i][j] = zero;

    gemm_core_bk64(xb, W, m0, n0, As, Bs, acc);

    const int tid = threadIdx.x;
    const int w = tid >> 6, lane = tid & 63;
    const int wm = (w & 1) << 6, wn = (w >> 1) << 6;
    const int c = lane & 15, quad = lane >> 4;
    // 0.125 (1/sqrt(64)) * log2(e): scores land in log2 domain
    const float qscale = (wsel == 0) ? 0.18033688f : 1.0f;

    #pragma unroll
    for (int j = 0; j < 4; ++j) {
        const int n_g = n0 + wn + j * 16 + c;
        const float bj = bias[n_g];
        const int h = n_g >> 6, d = n_g & 63;
        #pragma unroll
        for (int i = 0; i < 4; ++i) {
            const int mbase = m0 + wm + i * 16 + quad * 4;
            const int b = mbase >> 11;
            const int sbase = mbase & (SL - 1);
            if (wsel == 2) {
                ushort4 pk;
                pk.x = (ushort_t)f2bf(acc[i][j][0] + bj);
                pk.y = (ushort_t)f2bf(acc[i][j][1] + bj);
                pk.z = (ushort_t)f2bf(acc[i][j][2] + bj);
                pk.w = (ushort_t)f2bf(acc[i][j][3] + bj);
                *(ushort4*)&vo[(((size_t)(b * NH + h) * HD) + d) * SL + sbase] = pk;
            } else {
                ushort_t* dst = (wsel == 0) ? qo : ko;
                #pragma unroll
                for (int reg = 0; reg < 4; ++reg) {
                    const float v = (acc[i][j][reg] + bj) * qscale;
                    dst[(((size_t)(b * NH + h) * SL) + sbase + reg) * HD + d] =
                        (ushort_t)f2bf(v);
                }
            }
        }
    }
}

// ---------------------------------------------------------------------------
// MFMA flash attention, fixed-base softmax, 128-row q-tiles, 32 rows/wave.
//
// v3 (post-mortem of v2's spill disaster):
//  * v2's __launch_bounds__(256,5) forced the unified reg file to ~96/wave;
//    peak live set is ~140 -> ~40 regs spilled, 1.6 GB scratch traffic per
//    dispatch (WRITE_SIZE 16 MB -> 823 MB), 3.6x regression.  NEVER force a
//    wave bound below the live set.  Now plain __launch_bounds__(256): the
//    allocator is free, worst case 3 blocks/CU, zero scratch.
//  * Keep T14 async-STAGE split (harness-verified in v2): next kt's K/V are
//    loaded into registers and ds_write'n to LDS after the next loop-top
//    barrier, so global latency hides under compute instead of serializing
//    at a global_load_lds->barrier drain every iteration.
//  * Prefetch ISSUE point moved to after the softmax/Ps-write phase: sf[2][4]
//    (32 regs) is dead there, so kr/vr can reuse its slots -- gives the
//    allocator a shot at <=128 (4 blocks/CU).  Overlap window = P-read + PV
//    MFMA + loop-top barrier, enough to cover the mostly-L2 K/V latency.
//  * Ps XOR-swizzled stride 64 (verified in v2): LDS total exactly 32 KB.
// ---------------------------------------------------------------------------
__global__ __launch_bounds__(256) void attn_mfma_kernel(
    const ushort_t* __restrict__ q, const ushort_t* __restrict__ k,
    const ushort_t* __restrict__ vt, const int* __restrict__ mask,
    ushort_t* __restrict__ ao)
{
    __shared__ __align__(16) ushort_t Ks[64 * 64];    // 8 KB
    __shared__ __align__(16) ushort_t Vs[64 * 64];    // 8 KB
    __shared__ __align__(16) ushort_t Ps[128 * 64];   // 16 KB (swizzled)

    const int qt = blockIdx.x;    // 0..15
    const int bh = blockIdx.y;
    const int b = bh >> 4, h = bh & 15;
    const int tid = threadIdx.x;
    const int w = tid >> 6, lane = tid & 63;
    const int c = lane & 15, quad = lane >> 4;

    const ushort_t* qp = q  + (size_t)bh * SL * HD + (size_t)qt * 128 * HD;
    const ushort_t* kp = k  + (size_t)bh * SL * HD;
    const ushort_t* vp = vt + (size_t)bh * HD * SL;

    short8 qf[2][2];
    #pragma unroll
    for (int mi = 0; mi < 2; ++mi)
        #pragma unroll
        for (int ks = 0; ks < 2; ++ks)
            qf[mi][ks] = *(const short8*)&qp[(size_t)(w * 32 + mi * 16 + c) * HD
                                             + ks * 32 + quad * 8];

    float l_s[2][4] = {};
    f32x4 oa[2][4];
    const f32x4 zero = {0.f, 0.f, 0.f, 0.f};
    #pragma unroll
    for (int mi = 0; mi < 2; ++mi)
        #pragma unroll
        for (int ni = 0; ni < 4; ++ni) oa[mi][ni] = zero;

    // per-thread staging geometry: 2 chunks each of K and V per iteration.
    // chunk t = (rd*4+w)*64+lane covers row r = t>>3, col-chunk sc = t&7.
    // LDS slot s holds row s>>3, content chunk (s&7)^key(row) -- same layout
    // the old pre-swizzled global_load_lds produced, so reads are unchanged.
    uint4 kr[2], vr[2];
    #pragma unroll
    for (int rd = 0; rd < 2; ++rd) {
        const int t = (rd * 4 + w) * 64 + lane;
        const int r = t >> 3, sc = t & 7;
        kr[rd] = *(const uint4*)&kp[(size_t)r * HD + sc * 8];
        vr[rd] = *(const uint4*)&vp[(size_t)r * SL + sc * 8];
    }

    for (int kt = 0; kt < SL / 64; ++kt) {
        __syncthreads();          // prev compute done; drains prefetch vmcnt
        // write prefetched tile: K keyed (r>>2)&7 (QK^T reads row 4c+ni),
        // V keyed r&7 (PV reads row ni*16+c)
        #pragma unroll
        for (int rd = 0; rd < 2; ++rd) {
            const int t = (rd * 4 + w) * 64 + lane;
            const int r = t >> 3, sc = t & 7;
            *(uint4*)&Ks[(r * 8 + (sc ^ ((r >> 2) & 7))) * 8] = kr[rd];
            *(uint4*)&Vs[(r * 8 + (sc ^ (r & 7))) * 8] = vr[rd];
        }
        __syncthreads();          // writes visible to all waves

        // S = Q @ K^T, log2 domain. Column c of tile ni = key 4c+ni.
        f32x4 sf[2][4];
        #pragma unroll
        for (int mi = 0; mi < 2; ++mi)
            #pragma unroll
            for (int ni = 0; ni < 4; ++ni) sf[mi][ni] = zero;
        #pragma unroll
        for (int ni = 0; ni < 4; ++ni) {
            const int krow = 4 * c + ni;
            #pragma unroll
            for (int ks = 0; ks < 2; ++ks) {
                const short8 kf = *(const short8*)
                    &Ks[krow * 64 + (((ks * 4 + quad) ^ (c & 7)) << 3)];
                #pragma unroll
                for (int mi = 0; mi < 2; ++mi)
                    sf[mi][ni] = __builtin_amdgcn_mfma_f32_16x16x32_bf16(
                        qf[mi][ks], kf, sf[mi][ni], 0, 0, 0);
            }
        }

        const int4 mzv = *(const int4*)&mask[b * SL + kt * 64 + 4 * c];
        const int mz[4] = {mzv.x, mzv.y, mzv.z, mzv.w};

        #pragma unroll
        for (int mi = 0; mi < 2; ++mi) {
            #pragma unroll
            for (int reg = 0; reg < 4; ++reg) {
                float p[4];
                #pragma unroll
                for (int ni = 0; ni < 4; ++ni) {
                    float pv = __builtin_amdgcn_exp2f(sf[mi][ni][reg]);
                    p[ni] = (mz[ni] == 0) ? 0.f : pv;
                }
                l_s[mi][reg] += (p[0] + p[1]) + (p[2] + p[3]);
                union { float f; uint_t u; } u0, u1, u2, u3;
                u0.f = p[0]; u1.f = p[1]; u2.f = p[2]; u3.f = p[3];
                uint2 pk;
                pk.x = __builtin_amdgcn_perm(u1.u, u0.u, 0x07060302u);
                pk.y = __builtin_amdgcn_perm(u3.u, u2.u, 0x07060302u);
                // P row quad*4+reg, cols 4c..4c+3 -> chunk c>>1, half c&1
                const int prow = w * 32 + mi * 16 + quad * 4 + reg;
                *(uint2*)&Ps[prow * 64 + (((c >> 1) ^ (prow & 7)) * 8)
                             + ((c & 1) * 4)] = pk;
            }
        }
        // wave-local LDS round-trip: no barrier needed

        // issue next tile's K/V loads HERE: sf is dead (its regs are free for
        // kr/vr), and the loads stay in flight through P-read + PV + the next
        // loop-top barrier -- that barrier's implicit vmcnt drain is the
        // consume point.
        if (kt + 1 < SL / 64) {
            #pragma unroll
            for (int rd = 0; rd < 2; ++rd) {
                const int t = (rd * 4 + w) * 64 + lane;
                const int r = t >> 3, sc = t & 7;
                kr[rd] = *(const uint4*)&kp[(size_t)((kt + 1) * 64 + r) * HD + sc * 8];
                vr[rd] = *(const uint4*)&vp[(size_t)r * SL + (kt + 1) * 64 + sc * 8];
            }
        }

        short8 pf[2][2];
        #pragma unroll
        for (int mi = 0; mi < 2; ++mi)
            #pragma unroll
            for (int ks = 0; ks < 2; ++ks) {
                const int prow = w * 32 + mi * 16 + c;
                pf[mi][ks] = *(const short8*)
                    &Ps[prow * 64 + (((ks * 4 + quad) ^ (prow & 7)) << 3)];
            }
        #pragma unroll
        for (int ni = 0; ni < 4; ++ni) {
            const int n = ni * 16 + c;
            #pragma unroll
            for (int ks = 0; ks < 2; ++ks) {
                const short8 vf = *(const short8*)
                    &Vs[n * 64 + (((ks * 4 + quad) ^ (c & 7)) << 3)];
                #pragma unroll
                for (int mi = 0; mi < 2; ++mi)
                    oa[mi][ni] = __builtin_amdgcn_mfma_f32_16x16x32_bf16(
                        pf[mi][ks], vf, oa[mi][ni], 0, 0, 0);
            }
        }
    }

    #pragma unroll
    for (int mi = 0; mi < 2; ++mi) {
        #pragma unroll
        for (int reg = 0; reg < 4; ++reg) {
            float l = l_s[mi][reg];
            #pragma unroll
            for (int off = 1; off < 16; off <<= 1)
                l += __shfl_xor(l, off, 64);
            const float inv = 1.f / l;
            const int s_g = qt * 128 + w * 32 + mi * 16 + quad * 4 + reg;
            #pragma unroll
            for (int ni = 0; ni < 4; ++ni) {
                const int d = ni * 16 + c;
                ao[((size_t)(b * SL + s_g)) * HID + h * HD + d] =
                    (ushort_t)f2bf(oa[mi][ni][reg] * inv);
            }
        }
    }
}

// ---------------------------------------------------------------------------
// Output projection: out(fp32) = ao_bf @ Wo^T + bo. grid (8, 64).
// ---------------------------------------------------------------------------
__global__ __launch_bounds__(256) void out_mfma_kernel(
    const ushort_t* __restrict__ aob, const ushort_t* __restrict__ wob,
    const float* __restrict__ bo, float* __restrict__ out)
{
    __shared__ __align__(16) ushort_t As[128 * 64];
    __shared__ __align__(16) ushort_t Bs[128 * 64];

    const int m0 = blockIdx.y * 128, n0 = blockIdx.x * 128;

    f32x4 acc[4][4];
    const f32x4 zero = {0.f, 0.f, 0.f, 0.f};
    #pragma unroll
    for (int i = 0; i < 4; ++i)
        #pragma unroll
        for (int j = 0; j < 4; ++j) acc[i][j] = zero;

    gemm_core_bk64(aob, wob, m0, n0, As, Bs, acc);

    const int tid = threadIdx.x;
    const int w = tid >> 6, lane = tid & 63;
    const int wm = (w & 1) << 6, wn = (w >> 1) << 6;
    const int c = lane & 15, quad = lane >> 4;

    #pragma unroll
    for (int j = 0; j < 4; ++j) {
        const int n_g = n0 + wn + j * 16 + c;
        const float bj = bo[n_g];
        #pragma unroll
        for (int i = 0; i < 4; ++i) {
            const int mbase = m0 + wm + i * 16 + quad * 4;
            #pragma unroll
            for (int reg = 0; reg < 4; ++reg)
                out[(size_t)(mbase + reg) * HID + n_g] = acc[i][j][reg] + bj;
        }
    }
}

extern "C" void kernel_launch(void* const* d_in, const int* in_sizes, int n_in,
                              void* d_out, int out_size, void* d_ws, size_t ws_size,
                              hipStream_t stream)
{
    const float* x    = (const float*)d_in[0];
    const int*   mask = (const int*)d_in[1];
    const float* Wq   = (const float*)d_in[2];
    const float* bq   = (const float*)d_in[3];
    const float* Wk   = (const float*)d_in[4];
    const float* bk   = (const float*)d_in[5];
    const float* Wv   = (const float*)d_in[6];
    const float* bv   = (const float*)d_in[7];
    const float* Wo   = (const float*)d_in[8];
    const float* bo   = (const float*)d_in[9];
    float* out = (float*)d_out;

    ushort_t* p = (ushort_t*)d_ws;
    ushort_t* xb  = p; p += (size_t)MROWS * HID;
    ushort_t* wqb = p; p += (size_t)HID * HID;
    ushort_t* wkb = p; p += (size_t)HID * HID;
    ushort_t* wvb = p; p += (size_t)HID * HID;
    ushort_t* wob = p; p += (size_t)HID * HID;
    ushort_t* qb  = p; p += (size_t)MROWS * HID;
    ushort_t* kb  = p; p += (size_t)MROWS * HID;
    ushort_t* vtb = p; p += (size_t)MROWS * HID;
    ushort_t* aob = p; p += (size_t)MROWS * HID;

    cvt_bf16_kernel<<<dim3(512, 12), 256, 0, stream>>>(
        x, Wq, Wk, Wv, Wo, xb, wqb, wkb, wvb, wob);
    qkv_mfma_kernel<<<dim3(8, 64, 3), 256, 0, stream>>>(
        xb, wqb, wkb, wvb, bq, bk, bv, qb, kb, vtb);
    attn_mfma_kernel<<<dim3(16, 64), 256, 0, stream>>>(
        qb, kb, vtb, mask, aob);
    out_mfma_kernel<<<dim3(8, 64), 256, 0, stream>>>(
        aob, wob, bo, out);
}

// Round 3
// 376.913 us; speedup vs baseline: 1.4852x; 1.2398x over previous
//
#include <hip/hip_runtime.h>
#include <math.h>

#define HID 1024
#define NH  16
#define HD  64
#define NB  4
#define SL  2048
#define MROWS (NB * SL)   // 8192

typedef __attribute__((ext_vector_type(8))) short short8;
typedef __attribute__((ext_vector_type(4))) float f32x4;
typedef unsigned short ushort_t;
typedef unsigned int uint_t;

// fp32 -> bf16 bits, round-to-nearest-even
__device__ __forceinline__ uint_t f2bf(float x) {
    union { float f; uint_t u; } a; a.f = x;
    return (a.u + 0x7fffu + ((a.u >> 16) & 1u)) >> 16;
}

// async global->LDS, 16B per lane; LDS dest = wave-uniform base + lane*16
__device__ __forceinline__ void load_lds16(const void* g, void* l) {
    __builtin_amdgcn_global_load_lds(
        (const __attribute__((address_space(1))) void*)g,
        (__attribute__((address_space(3))) void*)l, 16, 0, 0);
}

// ---------------------------------------------------------------------------
// GEMM core: C(128x128) = A @ B^T, bf16, BK=64 (16 k-iters, 32 MFMA/wave/iter).
// LDS rows are 128 B = exactly 32 banks (row drops out of bank equation);
// chunks XOR-swizzled with r&7 (== c&7 at read) -> fragment b128 reads spread
// evenly over the 8 bank-groups.
// ---------------------------------------------------------------------------
__device__ __forceinline__ void gemm_core_bk64(
    const ushort_t* __restrict__ A, const ushort_t* __restrict__ B,
    const int m0, const int n0, ushort_t* As, ushort_t* Bs, f32x4 (&acc)[4][4])
{
    const int tid = threadIdx.x;
    const int w = tid >> 6, lane = tid & 63;
    const int wm = (w & 1) << 6, wn = (w >> 1) << 6;
    const int c = lane & 15, quad = lane >> 4;

    for (int k0 = 0; k0 < HID; k0 += 64) {
        __syncthreads();
        #pragma unroll
        for (int rd = 0; rd < 4; ++rd) {
            const int g = rd * 4 + w;            // wave-uniform group 0..15
            const int idx = g * 64 + lane;       // 16B-chunk id, 0..1023
            const int r = idx >> 3, sc = idx & 7;
            const int dc = sc ^ (r & 7);         // fetch permuted chunk
            load_lds16(&A[(size_t)(m0 + r) * HID + k0 + dc * 8], As + g * 512);
            load_lds16(&B[(size_t)(n0 + r) * HID + k0 + dc * 8], Bs + g * 512);
        }
        __syncthreads();

        #pragma unroll
        for (int ks = 0; ks < 2; ++ks) {
            short8 af[4], bf[4];
            #pragma unroll
            for (int i = 0; i < 4; ++i) {
                const int ra = wm + i * 16 + c;
                const int rb = wn + i * 16 + c;
                af[i] = *(const short8*)
                    &As[ra * 64 + ((((ks << 2) + quad) ^ (c & 7)) << 3)];
                bf[i] = *(const short8*)
                    &Bs[rb * 64 + ((((ks << 2) + quad) ^ (c & 7)) << 3)];
            }
            #pragma unroll
            for (int i = 0; i < 4; ++i)
                #pragma unroll
                for (int j = 0; j < 4; ++j)
                    acc[i][j] = __builtin_amdgcn_mfma_f32_16x16x32_bf16(
                        af[i], bf[j], acc[i][j], 0, 0, 0);
        }
    }
}

// ---------------------------------------------------------------------------
// fp32 -> bf16 conversion: 12 segments of 1M elems (x = 8 segs, 4 weights)
// ---------------------------------------------------------------------------
__global__ __launch_bounds__(256) void cvt_bf16_kernel(
    const float* __restrict__ x,
    const float* __restrict__ wq, const float* __restrict__ wk,
    const float* __restrict__ wv, const float* __restrict__ wo,
    ushort_t* __restrict__ xb, ushort_t* __restrict__ wqb,
    ushort_t* __restrict__ wkb, ushort_t* __restrict__ wvb,
    ushort_t* __restrict__ wob)
{
    const int seg = blockIdx.y;
    const float* src; ushort_t* dst;
    if (seg < 8)       { src = x + (size_t)seg * 1048576; dst = xb + (size_t)seg * 1048576; }
    else if (seg == 8) { src = wq; dst = wqb; }
    else if (seg == 9) { src = wk; dst = wkb; }
    else if (seg == 10){ src = wv; dst = wvb; }
    else               { src = wo; dst = wob; }
    const int i = (blockIdx.x * 256 + threadIdx.x) * 8;
    const float4 a = *(const float4*)&src[i];
    const float4 b = *(const float4*)&src[i + 4];
    uint4 o;
    o.x = f2bf(a.x) | (f2bf(a.y) << 16);
    o.y = f2bf(a.z) | (f2bf(a.w) << 16);
    o.z = f2bf(b.x) | (f2bf(b.y) << 16);
    o.w = f2bf(b.z) | (f2bf(b.w) << 16);
    *(uint4*)&dst[i] = o;
}

// ---------------------------------------------------------------------------
// QKV projection. grid (8 n-tiles, 64 m-tiles, 3 weights); 128x128 tile.
// Q pre-scaled by 0.125*log2(e); K as (B,H,S,D); V^T as (B,H,D,S).
// ---------------------------------------------------------------------------
__global__ __launch_bounds__(256) void qkv_mfma_kernel(
    const ushort_t* __restrict__ xb,
    const ushort_t* __restrict__ wqb, const ushort_t* __restrict__ wkb,
    const ushort_t* __restrict__ wvb,
    const float* __restrict__ bq, const float* __restrict__ bk,
    const float* __restrict__ bv,
    ushort_t* __restrict__ qo, ushort_t* __restrict__ ko,
    ushort_t* __restrict__ vo)
{
    __shared__ __align__(16) ushort_t As[128 * 64];   // 16 KB
    __shared__ __align__(16) ushort_t Bs[128 * 64];   // 16 KB

    const int wsel = blockIdx.z;
    const ushort_t* W    = (wsel == 0) ? wqb : (wsel == 1) ? wkb : wvb;
    const float*    bias = (wsel == 0) ? bq  : (wsel == 1) ? bk  : bv;
    const int m0 = blockIdx.y * 128, n0 = blockIdx.x * 128;

    f32x4 acc[4][4];
    const f32x4 zero = {0.f, 0.f, 0.f, 0.f};
    #pragma unroll
    for (int i = 0; i < 4; ++i)
        #pragma unroll
        for (int j = 0; j < 4; ++j) acc[i][j] = zero;

    gemm_core_bk64(xb, W, m0, n0, As, Bs, acc);

    const int tid = threadIdx.x;
    const int w = tid >> 6, lane = tid & 63;
    const int wm = (w & 1) << 6, wn = (w >> 1) << 6;
    const int c = lane & 15, quad = lane >> 4;
    // 0.125 (1/sqrt(64)) * log2(e): scores land in log2 domain
    const float qscale = (wsel == 0) ? 0.18033688f : 1.0f;

    #pragma unroll
    for (int j = 0; j < 4; ++j) {
        const int n_g = n0 + wn + j * 16 + c;
        const float bj = bias[n_g];
        const int h = n_g >> 6, d = n_g & 63;
        #pragma unroll
        for (int i = 0; i < 4; ++i) {
            const int mbase = m0 + wm + i * 16 + quad * 4;
            const int b = mbase >> 11;
            const int sbase = mbase & (SL - 1);
            if (wsel == 2) {
                ushort4 pk;
                pk.x = (ushort_t)f2bf(acc[i][j][0] + bj);
                pk.y = (ushort_t)f2bf(acc[i][j][1] + bj);
                pk.z = (ushort_t)f2bf(acc[i][j][2] + bj);
                pk.w = (ushort_t)f2bf(acc[i][j][3] + bj);
                *(ushort4*)&vo[(((size_t)(b * NH + h) * HD) + d) * SL + sbase] = pk;
            } else {
                ushort_t* dst = (wsel == 0) ? qo : ko;
                #pragma unroll
                for (int reg = 0; reg < 4; ++reg) {
                    const float v = (acc[i][j][reg] + bj) * qscale;
                    dst[(((size_t)(b * NH + h) * SL) + sbase + reg) * HD + d] =
                        (ushort_t)f2bf(v);
                }
            }
        }
    }
}

// ---------------------------------------------------------------------------
// MFMA flash attention, fixed-base softmax, 128-row q-tiles, 32 rows/wave.
//
// v4 (register-budget post-mortems of v2/v3):
//  * v2: __launch_bounds__(256,5) -> cap ~96 < live set -> 40-reg spill,
//    823 MB WRITE_SIZE, 3.6x regression.
//  * v3: NO min-waves bound -> backend derived its own occupancy target from
//    the small LDS footprint, capped VGPRs at 72 and spilled ~190 MB of
//    scratch writes.  Lesson: on this kernel the bound must be EXPLICIT and
//    must match the live set.
//  * v4: __launch_bounds__(256,4) -- the exact bound the 98 us baseline used
//    (cap 128).  Live set of the T14 structure ~110-120 (v1's 60 + 16
//    prefetch regs + scheduling overlap), fits under 128 with no spill at
//    unchanged 4-blocks/CU occupancy.
//  * Keep T14 async-STAGE split: prefetch K/V into regs AFTER softmax (sf
//    dead there -> its 32 slots recycle into kr/vr), ds_write at next
//    loop-top barrier.  Global latency hides under P-read + PV MFMA.
//  * Ps XOR-swizzled stride 64: LDS exactly 32 KB.
// ---------------------------------------------------------------------------
__global__ __launch_bounds__(256, 4) void attn_mfma_kernel(
    const ushort_t* __restrict__ q, const ushort_t* __restrict__ k,
    const ushort_t* __restrict__ vt, const int* __restrict__ mask,
    ushort_t* __restrict__ ao)
{
    __shared__ __align__(16) ushort_t Ks[64 * 64];    // 8 KB
    __shared__ __align__(16) ushort_t Vs[64 * 64];    // 8 KB
    __shared__ __align__(16) ushort_t Ps[128 * 64];   // 16 KB (swizzled)

    const int qt = blockIdx.x;    // 0..15
    const int bh = blockIdx.y;
    const int b = bh >> 4, h = bh & 15;
    const int tid = threadIdx.x;
    const int w = tid >> 6, lane = tid & 63;
    const int c = lane & 15, quad = lane >> 4;

    const ushort_t* qp = q  + (size_t)bh * SL * HD + (size_t)qt * 128 * HD;
    const ushort_t* kp = k  + (size_t)bh * SL * HD;
    const ushort_t* vp = vt + (size_t)bh * HD * SL;

    short8 qf[2][2];
    #pragma unroll
    for (int mi = 0; mi < 2; ++mi)
        #pragma unroll
        for (int ks = 0; ks < 2; ++ks)
            qf[mi][ks] = *(const short8*)&qp[(size_t)(w * 32 + mi * 16 + c) * HD
                                             + ks * 32 + quad * 8];

    float l_s[2][4] = {};
    f32x4 oa[2][4];
    const f32x4 zero = {0.f, 0.f, 0.f, 0.f};
    #pragma unroll
    for (int mi = 0; mi < 2; ++mi)
        #pragma unroll
        for (int ni = 0; ni < 4; ++ni) oa[mi][ni] = zero;

    // per-thread staging geometry: 2 chunks each of K and V per iteration.
    // chunk t = (rd*4+w)*64+lane covers row r = t>>3, col-chunk sc = t&7.
    // LDS slot s holds row s>>3, content chunk (s&7)^key(row) -- same layout
    // the old pre-swizzled global_load_lds produced, so reads are unchanged.
    uint4 kr[2], vr[2];
    #pragma unroll
    for (int rd = 0; rd < 2; ++rd) {
        const int t = (rd * 4 + w) * 64 + lane;
        const int r = t >> 3, sc = t & 7;
        kr[rd] = *(const uint4*)&kp[(size_t)r * HD + sc * 8];
        vr[rd] = *(const uint4*)&vp[(size_t)r * SL + sc * 8];
    }

    for (int kt = 0; kt < SL / 64; ++kt) {
        __syncthreads();          // prev compute done; drains prefetch vmcnt
        // write prefetched tile: K keyed (r>>2)&7 (QK^T reads row 4c+ni),
        // V keyed r&7 (PV reads row ni*16+c)
        #pragma unroll
        for (int rd = 0; rd < 2; ++rd) {
            const int t = (rd * 4 + w) * 64 + lane;
            const int r = t >> 3, sc = t & 7;
            *(uint4*)&Ks[(r * 8 + (sc ^ ((r >> 2) & 7))) * 8] = kr[rd];
            *(uint4*)&Vs[(r * 8 + (sc ^ (r & 7))) * 8] = vr[rd];
        }
        __syncthreads();          // writes visible to all waves

        // S = Q @ K^T, log2 domain. Column c of tile ni = key 4c+ni.
        f32x4 sf[2][4];
        #pragma unroll
        for (int mi = 0; mi < 2; ++mi)
            #pragma unroll
            for (int ni = 0; ni < 4; ++ni) sf[mi][ni] = zero;
        #pragma unroll
        for (int ni = 0; ni < 4; ++ni) {
            const int krow = 4 * c + ni;
            #pragma unroll
            for (int ks = 0; ks < 2; ++ks) {
                const short8 kf = *(const short8*)
                    &Ks[krow * 64 + (((ks * 4 + quad) ^ (c & 7)) << 3)];
                #pragma unroll
                for (int mi = 0; mi < 2; ++mi)
                    sf[mi][ni] = __builtin_amdgcn_mfma_f32_16x16x32_bf16(
                        qf[mi][ks], kf, sf[mi][ni], 0, 0, 0);
            }
        }

        const int4 mzv = *(const int4*)&mask[b * SL + kt * 64 + 4 * c];
        const int mz[4] = {mzv.x, mzv.y, mzv.z, mzv.w};

        #pragma unroll
        for (int mi = 0; mi < 2; ++mi) {
            #pragma unroll
            for (int reg = 0; reg < 4; ++reg) {
                float p[4];
                #pragma unroll
                for (int ni = 0; ni < 4; ++ni) {
                    float pv = __builtin_amdgcn_exp2f(sf[mi][ni][reg]);
                    p[ni] = (mz[ni] == 0) ? 0.f : pv;
                }
                l_s[mi][reg] += (p[0] + p[1]) + (p[2] + p[3]);
                union { float f; uint_t u; } u0, u1, u2, u3;
                u0.f = p[0]; u1.f = p[1]; u2.f = p[2]; u3.f = p[3];
                uint2 pk;
                pk.x = __builtin_amdgcn_perm(u1.u, u0.u, 0x07060302u);
                pk.y = __builtin_amdgcn_perm(u3.u, u2.u, 0x07060302u);
                // P row quad*4+reg, cols 4c..4c+3 -> chunk c>>1, half c&1
                const int prow = w * 32 + mi * 16 + quad * 4 + reg;
                *(uint2*)&Ps[prow * 64 + (((c >> 1) ^ (prow & 7)) * 8)
                             + ((c & 1) * 4)] = pk;
            }
        }
        // wave-local LDS round-trip: no barrier needed

        // issue next tile's K/V loads HERE: sf is dead (its regs are free for
        // kr/vr), and the loads stay in flight through P-read + PV + the next
        // loop-top barrier -- that barrier's implicit vmcnt drain is the
        // consume point.
        if (kt + 1 < SL / 64) {
            #pragma unroll
            for (int rd = 0; rd < 2; ++rd) {
                const int t = (rd * 4 + w) * 64 + lane;
                const int r = t >> 3, sc = t & 7;
                kr[rd] = *(const uint4*)&kp[(size_t)((kt + 1) * 64 + r) * HD + sc * 8];
                vr[rd] = *(const uint4*)&vp[(size_t)r * SL + (kt + 1) * 64 + sc * 8];
            }
        }

        short8 pf[2][2];
        #pragma unroll
        for (int mi = 0; mi < 2; ++mi)
            #pragma unroll
            for (int ks = 0; ks < 2; ++ks) {
                const int prow = w * 32 + mi * 16 + c;
                pf[mi][ks] = *(const short8*)
                    &Ps[prow * 64 + (((ks * 4 + quad) ^ (prow & 7)) << 3)];
            }
        #pragma unroll
        for (int ni = 0; ni < 4; ++ni) {
            const int n = ni * 16 + c;
            #pragma unroll
            for (int ks = 0; ks < 2; ++ks) {
                const short8 vf = *(const short8*)
                    &Vs[n * 64 + (((ks * 4 + quad) ^ (c & 7)) << 3)];
                #pragma unroll
                for (int mi = 0; mi < 2; ++mi)
                    oa[mi][ni] = __builtin_amdgcn_mfma_f32_16x16x32_bf16(
                        pf[mi][ks], vf, oa[mi][ni], 0, 0, 0);
            }
        }
    }

    #pragma unroll
    for (int mi = 0; mi < 2; ++mi) {
        #pragma unroll
        for (int reg = 0; reg < 4; ++reg) {
            float l = l_s[mi][reg];
            #pragma unroll
            for (int off = 1; off < 16; off <<= 1)
                l += __shfl_xor(l, off, 64);
            const float inv = 1.f / l;
            const int s_g = qt * 128 + w * 32 + mi * 16 + quad * 4 + reg;
            #pragma unroll
            for (int ni = 0; ni < 4; ++ni) {
                const int d = ni * 16 + c;
                ao[((size_t)(b * SL + s_g)) * HID + h * HD + d] =
                    (ushort_t)f2bf(oa[mi][ni][reg] * inv);
            }
        }
    }
}

// ---------------------------------------------------------------------------
// Output projection: out(fp32) = ao_bf @ Wo^T + bo. grid (8, 64).
// ---------------------------------------------------------------------------
__global__ __launch_bounds__(256) void out_mfma_kernel(
    const ushort_t* __restrict__ aob, const ushort_t* __restrict__ wob,
    const float* __restrict__ bo, float* __restrict__ out)
{
    __shared__ __align__(16) ushort_t As[128 * 64];
    __shared__ __align__(16) ushort_t Bs[128 * 64];

    const int m0 = blockIdx.y * 128, n0 = blockIdx.x * 128;

    f32x4 acc[4][4];
    const f32x4 zero = {0.f, 0.f, 0.f, 0.f};
    #pragma unroll
    for (int i = 0; i < 4; ++i)
        #pragma unroll
        for (int j = 0; j < 4; ++j) acc[i][j] = zero;

    gemm_core_bk64(aob, wob, m0, n0, As, Bs, acc);

    const int tid = threadIdx.x;
    const int w = tid >> 6, lane = tid & 63;
    const int wm = (w & 1) << 6, wn = (w >> 1) << 6;
    const int c = lane & 15, quad = lane >> 4;

    #pragma unroll
    for (int j = 0; j < 4; ++j) {
        const int n_g = n0 + wn + j * 16 + c;
        const float bj = bo[n_g];
        #pragma unroll
        for (int i = 0; i < 4; ++i) {
            const int mbase = m0 + wm + i * 16 + quad * 4;
            #pragma unroll
            for (int reg = 0; reg < 4; ++reg)
                out[(size_t)(mbase + reg) * HID + n_g] = acc[i][j][reg] + bj;
        }
    }
}

extern "C" void kernel_launch(void* const* d_in, const int* in_sizes, int n_in,
                              void* d_out, int out_size, void* d_ws, size_t ws_size,
                              hipStream_t stream)
{
    const float* x    = (const float*)d_in[0];
    const int*   mask = (const int*)d_in[1];
    const float* Wq   = (const float*)d_in[2];
    const float* bq   = (const float*)d_in[3];
    const float* Wk   = (const float*)d_in[4];
    const float* bk   = (const float*)d_in[5];
    const float* Wv   = (const float*)d_in[6];
    const float* bv   = (const float*)d_in[7];
    const float* Wo   = (const float*)d_in[8];
    const float* bo   = (const float*)d_in[9];
    float* out = (float*)d_out;

    ushort_t* p = (ushort_t*)d_ws;
    ushort_t* xb  = p; p += (size_t)MROWS * HID;
    ushort_t* wqb = p; p += (size_t)HID * HID;
    ushort_t* wkb = p; p += (size_t)HID * HID;
    ushort_t* wvb = p; p += (size_t)HID * HID;
    ushort_t* wob = p; p += (size_t)HID * HID;
    ushort_t* qb  = p; p += (size_t)MROWS * HID;
    ushort_t* kb  = p; p += (size_t)MROWS * HID;
    ushort_t* vtb = p; p += (size_t)MROWS * HID;
    ushort_t* aob = p; p += (size_t)MROWS * HID;

    cvt_bf16_kernel<<<dim3(512, 12), 256, 0, stream>>>(
        x, Wq, Wk, Wv, Wo, xb, wqb, wkb, wvb, wob);
    qkv_mfma_kernel<<<dim3(8, 64, 3), 256, 0, stream>>>(
        xb, wqb, wkb, wvb, bq, bk, bv, qb, kb, vtb);
    attn_mfma_kernel<<<dim3(16, 64), 256, 0, stream>>>(
        qb, kb, vtb, mask, aob);
    out_mfma_kernel<<<dim3(8, 64), 256, 0, stream>>>(
        aob, wob, bo, out);
}

// Round 4
// 304.238 us; speedup vs baseline: 1.8400x; 1.2389x over previous
//
#include <hip/hip_runtime.h>
#include <math.h>

#define HID 1024
#define NH  16
#define HD  64
#define NB  4
#define SL  2048
#define MROWS (NB * SL)   // 8192

typedef __attribute__((ext_vector_type(8))) short short8;
typedef __attribute__((ext_vector_type(4))) float f32x4;
typedef unsigned short ushort_t;
typedef unsigned int uint_t;

// fp32 -> bf16 bits, round-to-nearest-even
__device__ __forceinline__ uint_t f2bf(float x) {
    union { float f; uint_t u; } a; a.f = x;
    return (a.u + 0x7fffu + ((a.u >> 16) & 1u)) >> 16;
}

// async global->LDS, 16B per lane; LDS dest = wave-uniform base + lane*16
__device__ __forceinline__ void load_lds16(const void* g, void* l) {
    __builtin_amdgcn_global_load_lds(
        (const __attribute__((address_space(1))) void*)g,
        (__attribute__((address_space(3))) void*)l, 16, 0, 0);
}

// ---------------------------------------------------------------------------
// GEMM core: C(128x128) = A @ B^T, bf16, BK=64 (16 k-iters, 32 MFMA/wave/iter).
// LDS rows are 128 B = exactly 32 banks (row drops out of bank equation);
// chunks XOR-swizzled with r&7 (== c&7 at read) -> fragment b128 reads spread
// evenly over the 8 bank-groups.
// ---------------------------------------------------------------------------
__device__ __forceinline__ void gemm_core_bk64(
    const ushort_t* __restrict__ A, const ushort_t* __restrict__ B,
    const int m0, const int n0, ushort_t* As, ushort_t* Bs, f32x4 (&acc)[4][4])
{
    const int tid = threadIdx.x;
    const int w = tid >> 6, lane = tid & 63;
    const int wm = (w & 1) << 6, wn = (w >> 1) << 6;
    const int c = lane & 15, quad = lane >> 4;

    for (int k0 = 0; k0 < HID; k0 += 64) {
        __syncthreads();
        #pragma unroll
        for (int rd = 0; rd < 4; ++rd) {
            const int g = rd * 4 + w;            // wave-uniform group 0..15
            const int idx = g * 64 + lane;       // 16B-chunk id, 0..1023
            const int r = idx >> 3, sc = idx & 7;
            const int dc = sc ^ (r & 7);         // fetch permuted chunk
            load_lds16(&A[(size_t)(m0 + r) * HID + k0 + dc * 8], As + g * 512);
            load_lds16(&B[(size_t)(n0 + r) * HID + k0 + dc * 8], Bs + g * 512);
        }
        __syncthreads();

        #pragma unroll
        for (int ks = 0; ks < 2; ++ks) {
            short8 af[4], bf[4];
            #pragma unroll
            for (int i = 0; i < 4; ++i) {
                const int ra = wm + i * 16 + c;
                const int rb = wn + i * 16 + c;
                af[i] = *(const short8*)
                    &As[ra * 64 + ((((ks << 2) + quad) ^ (c & 7)) << 3)];
                bf[i] = *(const short8*)
                    &Bs[rb * 64 + ((((ks << 2) + quad) ^ (c & 7)) << 3)];
            }
            #pragma unroll
            for (int i = 0; i < 4; ++i)
                #pragma unroll
                for (int j = 0; j < 4; ++j)
                    acc[i][j] = __builtin_amdgcn_mfma_f32_16x16x32_bf16(
                        af[i], bf[j], acc[i][j], 0, 0, 0);
        }
    }
}

// ---------------------------------------------------------------------------
// fp32 -> bf16 conversion: 12 segments of 1M elems (x = 8 segs, 4 weights)
// ---------------------------------------------------------------------------
__global__ __launch_bounds__(256) void cvt_bf16_kernel(
    const float* __restrict__ x,
    const float* __restrict__ wq, const float* __restrict__ wk,
    const float* __restrict__ wv, const float* __restrict__ wo,
    ushort_t* __restrict__ xb, ushort_t* __restrict__ wqb,
    ushort_t* __restrict__ wkb, ushort_t* __restrict__ wvb,
    ushort_t* __restrict__ wob)
{
    const int seg = blockIdx.y;
    const float* src; ushort_t* dst;
    if (seg < 8)       { src = x + (size_t)seg * 1048576; dst = xb + (size_t)seg * 1048576; }
    else if (seg == 8) { src = wq; dst = wqb; }
    else if (seg == 9) { src = wk; dst = wkb; }
    else if (seg == 10){ src = wv; dst = wvb; }
    else               { src = wo; dst = wob; }
    const int i = (blockIdx.x * 256 + threadIdx.x) * 8;
    const float4 a = *(const float4*)&src[i];
    const float4 b = *(const float4*)&src[i + 4];
    uint4 o;
    o.x = f2bf(a.x) | (f2bf(a.y) << 16);
    o.y = f2bf(a.z) | (f2bf(a.w) << 16);
    o.z = f2bf(b.x) | (f2bf(b.y) << 16);
    o.w = f2bf(b.z) | (f2bf(b.w) << 16);
    *(uint4*)&dst[i] = o;
}

// ---------------------------------------------------------------------------
// QKV projection. grid (8 n-tiles, 64 m-tiles, 3 weights); 128x128 tile.
// Q pre-scaled by 0.125*log2(e); K as (B,H,S,D); V^T as (B,H,D,S).
// ---------------------------------------------------------------------------
__global__ __launch_bounds__(256) void qkv_mfma_kernel(
    const ushort_t* __restrict__ xb,
    const ushort_t* __restrict__ wqb, const ushort_t* __restrict__ wkb,
    const ushort_t* __restrict__ wvb,
    const float* __restrict__ bq, const float* __restrict__ bk,
    const float* __restrict__ bv,
    ushort_t* __restrict__ qo, ushort_t* __restrict__ ko,
    ushort_t* __restrict__ vo)
{
    __shared__ __align__(16) ushort_t As[128 * 64];   // 16 KB
    __shared__ __align__(16) ushort_t Bs[128 * 64];   // 16 KB

    const int wsel = blockIdx.z;
    const ushort_t* W    = (wsel == 0) ? wqb : (wsel == 1) ? wkb : wvb;
    const float*    bias = (wsel == 0) ? bq  : (wsel == 1) ? bk  : bv;
    const int m0 = blockIdx.y * 128, n0 = blockIdx.x * 128;

    f32x4 acc[4][4];
    const f32x4 zero = {0.f, 0.f, 0.f, 0.f};
    #pragma unroll
    for (int i = 0; i < 4; ++i)
        #pragma unroll
        for (int j = 0; j < 4; ++j) acc[i][j] = zero;

    gemm_core_bk64(xb, W, m0, n0, As, Bs, acc);

    const int tid = threadIdx.x;
    const int w = tid >> 6, lane = tid & 63;
    const int wm = (w & 1) << 6, wn = (w >> 1) << 6;
    const int c = lane & 15, quad = lane >> 4;
    // 0.125 (1/sqrt(64)) * log2(e): scores land in log2 domain
    const float qscale = (wsel == 0) ? 0.18033688f : 1.0f;

    #pragma unroll
    for (int j = 0; j < 4; ++j) {
        const int n_g = n0 + wn + j * 16 + c;
        const float bj = bias[n_g];
        const int h = n_g >> 6, d = n_g & 63;
        #pragma unroll
        for (int i = 0; i < 4; ++i) {
            const int mbase = m0 + wm + i * 16 + quad * 4;
            const int b = mbase >> 11;
            const int sbase = mbase & (SL - 1);
            if (wsel == 2) {
                ushort4 pk;
                pk.x = (ushort_t)f2bf(acc[i][j][0] + bj);
                pk.y = (ushort_t)f2bf(acc[i][j][1] + bj);
                pk.z = (ushort_t)f2bf(acc[i][j][2] + bj);
                pk.w = (ushort_t)f2bf(acc[i][j][3] + bj);
                *(ushort4*)&vo[(((size_t)(b * NH + h) * HD) + d) * SL + sbase] = pk;
            } else {
                ushort_t* dst = (wsel == 0) ? qo : ko;
                #pragma unroll
                for (int reg = 0; reg < 4; ++reg) {
                    const float v = (acc[i][j][reg] + bj) * qscale;
                    dst[(((size_t)(b * NH + h) * SL) + sbase + reg) * HD + d] =
                        (ushort_t)f2bf(v);
                }
            }
        }
    }
}

// ---------------------------------------------------------------------------
// MFMA flash attention, fixed-base softmax, 128-row q-tiles, 32 rows/wave.
//
// v5 (post-mortems of v2/v3/v4): register-prefetch T14 spills on this kernel
// under EVERY bound tried (v2 cap96, v3 unbounded, v4 cap128) -- the MFMA
// accumulators occupy the AGPR side of the unified file and the arch-VGPR
// side can't also hold kr/vr prefetch + pf + qf.  Abandoned.
//
// v5 keeps v1's global_load_lds staging (ZERO staging registers -- that is
// the point of the direct-to-LDS path) and instead hides the staging latency
// with a double-buffered 2-phase pipeline (catalog T3 "minimum 2-phase",
// m230: 2ph = 92% of 8ph):
//
//   stage(buf0, tile0)
//   loop kt:  __syncthreads()            // drains tile-kt loads, which had
//                                        // the whole PREVIOUS compute to fly
//             stage(buf[nxt], tile kt+1) // flies during THIS compute
//             compute(buf[cur])
//
// One barrier per iteration (v1 had two), and its implicit vmcnt(0) drain
// only waits on loads issued a full compute-phase ago.  stage(buf[nxt])
// writes the buffer last READ in iteration kt-1, finished by all waves
// before the barrier -> race-free.  Loop unrolled x2 so cur/nxt are
// compile-time and LDS objects are static (no runtime-indexed aliasing).
//
// LDS: 2*8 (K) + 2*8 (V) + 16 (Ps swizzled) = 48 KB -> 3 blocks/CU.
// __launch_bounds__(256,3) matches that cap: reg budget ~170, live set ~60,
// no spill possible.
// ---------------------------------------------------------------------------
__global__ __launch_bounds__(256, 3) void attn_mfma_kernel(
    const ushort_t* __restrict__ q, const ushort_t* __restrict__ k,
    const ushort_t* __restrict__ vt, const int* __restrict__ mask,
    ushort_t* __restrict__ ao)
{
    __shared__ __align__(16) ushort_t Ks[2][64 * 64];   // 16 KB
    __shared__ __align__(16) ushort_t Vs[2][64 * 64];   // 16 KB
    __shared__ __align__(16) ushort_t Ps[128 * 64];     // 16 KB (swizzled)

    const int qt = blockIdx.x;    // 0..15
    const int bh = blockIdx.y;
    const int b = bh >> 4, h = bh & 15;
    const int tid = threadIdx.x;
    const int w = tid >> 6, lane = tid & 63;
    const int c = lane & 15, quad = lane >> 4;

    const ushort_t* qp = q  + (size_t)bh * SL * HD + (size_t)qt * 128 * HD;
    const ushort_t* kp = k  + (size_t)bh * SL * HD;
    const ushort_t* vp = vt + (size_t)bh * HD * SL;

    // staging geometry (identical to the verified v1 addressing):
    // per tile, 512 16B-chunks per array; group g = rd*4+w, chunk t = g*64+lane,
    // row r = t>>3, col-chunk sc = t&7.  Global source pre-swizzled:
    // K keyed (r>>2)&7 (QK^T reads row 4c+ni), V keyed r&7 (PV reads ni*16+c).
    const int t0 = (0 * 4 + w) * 64 + lane;
    const int t1 = (1 * 4 + w) * 64 + lane;
    const int r0 = t0 >> 3, sc0 = t0 & 7;
    const int r1 = t1 >> 3, sc1 = t1 & 7;
    const int dck0 = sc0 ^ ((r0 >> 2) & 7), dcv0 = sc0 ^ (r0 & 7);
    const int dck1 = sc1 ^ ((r1 >> 2) & 7), dcv1 = sc1 ^ (r1 & 7);

    // prologue: stage tile 0 into buffer 0
    load_lds16(&kp[(size_t)r0 * HD + dck0 * 8],            Ks[0] + (0 * 4 + w) * 512);
    load_lds16(&vp[(size_t)r0 * SL + 0 + dcv0 * 8],        Vs[0] + (0 * 4 + w) * 512);
    load_lds16(&kp[(size_t)r1 * HD + dck1 * 8],            Ks[0] + (1 * 4 + w) * 512);
    load_lds16(&vp[(size_t)r1 * SL + 0 + dcv1 * 8],        Vs[0] + (1 * 4 + w) * 512);

    short8 qf[2][2];
    #pragma unroll
    for (int mi = 0; mi < 2; ++mi)
        #pragma unroll
        for (int ks = 0; ks < 2; ++ks)
            qf[mi][ks] = *(const short8*)&qp[(size_t)(w * 32 + mi * 16 + c) * HD
                                             + ks * 32 + quad * 8];

    float l_s[2][4] = {};
    f32x4 oa[2][4];
    const f32x4 zero = {0.f, 0.f, 0.f, 0.f};
    #pragma unroll
    for (int mi = 0; mi < 2; ++mi)
        #pragma unroll
        for (int ni = 0; ni < 4; ++ni) oa[mi][ni] = zero;

    for (int kt0 = 0; kt0 < SL / 64; kt0 += 2) {
        #pragma unroll
        for (int half = 0; half < 2; ++half) {
            const int kt = kt0 + half;          // runtime base, static parity
            const int cur = half, nxt = half ^ 1;

            // drains: tile-kt loads complete (they flew during the previous
            // compute); all waves done reading buf[nxt] (iteration kt-1)
            __syncthreads();

            // issue next tile's loads into the other buffer
            if (kt + 1 < SL / 64) {
                const int kc = (kt + 1) * 64;
                load_lds16(&kp[(size_t)(kc + r0) * HD + dck0 * 8], Ks[nxt] + (0 * 4 + w) * 512);
                load_lds16(&vp[(size_t)r0 * SL + kc + dcv0 * 8],   Vs[nxt] + (0 * 4 + w) * 512);
                load_lds16(&kp[(size_t)(kc + r1) * HD + dck1 * 8], Ks[nxt] + (1 * 4 + w) * 512);
                load_lds16(&vp[(size_t)r1 * SL + kc + dcv1 * 8],   Vs[nxt] + (1 * 4 + w) * 512);
            }

            // ---- compute on buf[cur] ----
            // S = Q @ K^T, log2 domain. Column c of tile ni = key 4c+ni.
            f32x4 sf[2][4];
            #pragma unroll
            for (int mi = 0; mi < 2; ++mi)
                #pragma unroll
                for (int ni = 0; ni < 4; ++ni) sf[mi][ni] = zero;
            #pragma unroll
            for (int ni = 0; ni < 4; ++ni) {
                const int krow = 4 * c + ni;
                #pragma unroll
                for (int ks = 0; ks < 2; ++ks) {
                    const short8 kf = *(const short8*)
                        &Ks[cur][krow * 64 + (((ks * 4 + quad) ^ (c & 7)) << 3)];
                    #pragma unroll
                    for (int mi = 0; mi < 2; ++mi)
                        sf[mi][ni] = __builtin_amdgcn_mfma_f32_16x16x32_bf16(
                            qf[mi][ks], kf, sf[mi][ni], 0, 0, 0);
                }
            }

            const int4 mzv = *(const int4*)&mask[b * SL + kt * 64 + 4 * c];
            const int mz[4] = {mzv.x, mzv.y, mzv.z, mzv.w};

            #pragma unroll
            for (int mi = 0; mi < 2; ++mi) {
                #pragma unroll
                for (int reg = 0; reg < 4; ++reg) {
                    float p[4];
                    #pragma unroll
                    for (int ni = 0; ni < 4; ++ni) {
                        float pv = __builtin_amdgcn_exp2f(sf[mi][ni][reg]);
                        p[ni] = (mz[ni] == 0) ? 0.f : pv;
                    }
                    l_s[mi][reg] += (p[0] + p[1]) + (p[2] + p[3]);
                    union { float f; uint_t u; } u0, u1, u2, u3;
                    u0.f = p[0]; u1.f = p[1]; u2.f = p[2]; u3.f = p[3];
                    uint2 pk;
                    pk.x = __builtin_amdgcn_perm(u1.u, u0.u, 0x07060302u);
                    pk.y = __builtin_amdgcn_perm(u3.u, u2.u, 0x07060302u);
                    // P row quad*4+reg, cols 4c..4c+3 -> chunk c>>1, half c&1
                    const int prow = w * 32 + mi * 16 + quad * 4 + reg;
                    *(uint2*)&Ps[prow * 64 + (((c >> 1) ^ (prow & 7)) * 8)
                                 + ((c & 1) * 4)] = pk;
                }
            }
            // wave-local LDS round-trip: no barrier needed

            short8 pf[2][2];
            #pragma unroll
            for (int mi = 0; mi < 2; ++mi)
                #pragma unroll
                for (int ks = 0; ks < 2; ++ks) {
                    const int prow = w * 32 + mi * 16 + c;
                    pf[mi][ks] = *(const short8*)
                        &Ps[prow * 64 + (((ks * 4 + quad) ^ (prow & 7)) << 3)];
                }
            #pragma unroll
            for (int ni = 0; ni < 4; ++ni) {
                const int n = ni * 16 + c;
                #pragma unroll
                for (int ks = 0; ks < 2; ++ks) {
                    const short8 vf = *(const short8*)
                        &Vs[cur][n * 64 + (((ks * 4 + quad) ^ (c & 7)) << 3)];
                    #pragma unroll
                    for (int mi = 0; mi < 2; ++mi)
                        oa[mi][ni] = __builtin_amdgcn_mfma_f32_16x16x32_bf16(
                            pf[mi][ks], vf, oa[mi][ni], 0, 0, 0);
                }
            }
        }
    }

    #pragma unroll
    for (int mi = 0; mi < 2; ++mi) {
        #pragma unroll
        for (int reg = 0; reg < 4; ++reg) {
            float l = l_s[mi][reg];
            #pragma unroll
            for (int off = 1; off < 16; off <<= 1)
                l += __shfl_xor(l, off, 64);
            const float inv = 1.f / l;
            const int s_g = qt * 128 + w * 32 + mi * 16 + quad * 4 + reg;
            #pragma unroll
            for (int ni = 0; ni < 4; ++ni) {
                const int d = ni * 16 + c;
                ao[((size_t)(b * SL + s_g)) * HID + h * HD + d] =
                    (ushort_t)f2bf(oa[mi][ni][reg] * inv);
            }
        }
    }
}

// ---------------------------------------------------------------------------
// Output projection: out(fp32) = ao_bf @ Wo^T + bo. grid (8, 64).
// ---------------------------------------------------------------------------
__global__ __launch_bounds__(256) void out_mfma_kernel(
    const ushort_t* __restrict__ aob, const ushort_t* __restrict__ wob,
    const float* __restrict__ bo, float* __restrict__ out)
{
    __shared__ __align__(16) ushort_t As[128 * 64];
    __shared__ __align__(16) ushort_t Bs[128 * 64];

    const int m0 = blockIdx.y * 128, n0 = blockIdx.x * 128;

    f32x4 acc[4][4];
    const f32x4 zero = {0.f, 0.f, 0.f, 0.f};
    #pragma unroll
    for (int i = 0; i < 4; ++i)
        #pragma unroll
        for (int j = 0; j < 4; ++j) acc[i][j] = zero;

    gemm_core_bk64(aob, wob, m0, n0, As, Bs, acc);

    const int tid = threadIdx.x;
    const int w = tid >> 6, lane = tid & 63;
    const int wm = (w & 1) << 6, wn = (w >> 1) << 6;
    const int c = lane & 15, quad = lane >> 4;

    #pragma unroll
    for (int j = 0; j < 4; ++j) {
        const int n_g = n0 + wn + j * 16 + c;
        const float bj = bo[n_g];
        #pragma unroll
        for (int i = 0; i < 4; ++i) {
            const int mbase = m0 + wm + i * 16 + quad * 4;
            #pragma unroll
            for (int reg = 0; reg < 4; ++reg)
                out[(size_t)(mbase + reg) * HID + n_g] = acc[i][j][reg] + bj;
        }
    }
}

extern "C" void kernel_launch(void* const* d_in, const int* in_sizes, int n_in,
                              void* d_out, int out_size, void* d_ws, size_t ws_size,
                              hipStream_t stream)
{
    const float* x    = (const float*)d_in[0];
    const int*   mask = (const int*)d_in[1];
    const float* Wq   = (const float*)d_in[2];
    const float* bq   = (const float*)d_in[3];
    const float* Wk   = (const float*)d_in[4];
    const float* bk   = (const float*)d_in[5];
    const float* Wv   = (const float*)d_in[6];
    const float* bv   = (const float*)d_in[7];
    const float* Wo   = (const float*)d_in[8];
    const float* bo   = (const float*)d_in[9];
    float* out = (float*)d_out;

    ushort_t* p = (ushort_t*)d_ws;
    ushort_t* xb  = p; p += (size_t)MROWS * HID;
    ushort_t* wqb = p; p += (size_t)HID * HID;
    ushort_t* wkb = p; p += (size_t)HID * HID;
    ushort_t* wvb = p; p += (size_t)HID * HID;
    ushort_t* wob = p; p += (size_t)HID * HID;
    ushort_t* qb  = p; p += (size_t)MROWS * HID;
    ushort_t* kb  = p; p += (size_t)MROWS * HID;
    ushort_t* vtb = p; p += (size_t)MROWS * HID;
    ushort_t* aob = p; p += (size_t)MROWS * HID;

    cvt_bf16_kernel<<<dim3(512, 12), 256, 0, stream>>>(
        x, Wq, Wk, Wv, Wo, xb, wqb, wkb, wvb, wob);
    qkv_mfma_kernel<<<dim3(8, 64, 3), 256, 0, stream>>>(
        xb, wqb, wkb, wvb, bq, bk, bv, qb, kb, vtb);
    attn_mfma_kernel<<<dim3(16, 64), 256, 0, stream>>>(
        qb, kb, vtb, mask, aob);
    out_mfma_kernel<<<dim3(8, 64), 256, 0, stream>>>(
        aob, wob, bo, out);
}

// Round 5
// 295.983 us; speedup vs baseline: 1.8913x; 1.0279x over previous
//
#include <hip/hip_runtime.h>
#include <math.h>

#define HID 1024
#define NH  16
#define HD  64
#define NB  4
#define SL  2048
#define MROWS (NB * SL)   // 8192

typedef __attribute__((ext_vector_type(8))) short short8;
typedef __attribute__((ext_vector_type(4))) float f32x4;
typedef unsigned short ushort_t;
typedef unsigned int uint_t;

// fp32 -> bf16 bits, round-to-nearest-even
__device__ __forceinline__ uint_t f2bf(float x) {
    union { float f; uint_t u; } a; a.f = x;
    return (a.u + 0x7fffu + ((a.u >> 16) & 1u)) >> 16;
}

// async global->LDS, 16B per lane; LDS dest = wave-uniform base + lane*16
__device__ __forceinline__ void load_lds16(const void* g, void* l) {
    __builtin_amdgcn_global_load_lds(
        (const __attribute__((address_space(1))) void*)g,
        (__attribute__((address_space(3))) void*)l, 16, 0, 0);
}

// ---------------------------------------------------------------------------
// GEMM core: C(128x128) = A @ B^T, bf16, BK=64 (16 k-iters, 32 MFMA/wave/iter).
// LDS rows are 128 B = exactly 32 banks (row drops out of bank equation);
// chunks XOR-swizzled with r&7 (== c&7 at read) -> fragment b128 reads spread
// evenly over the 8 bank-groups.
// ---------------------------------------------------------------------------
__device__ __forceinline__ void gemm_core_bk64(
    const ushort_t* __restrict__ A, const ushort_t* __restrict__ B,
    const int m0, const int n0, ushort_t* As, ushort_t* Bs, f32x4 (&acc)[4][4])
{
    const int tid = threadIdx.x;
    const int w = tid >> 6, lane = tid & 63;
    const int wm = (w & 1) << 6, wn = (w >> 1) << 6;
    const int c = lane & 15, quad = lane >> 4;

    for (int k0 = 0; k0 < HID; k0 += 64) {
        __syncthreads();
        #pragma unroll
        for (int rd = 0; rd < 4; ++rd) {
            const int g = rd * 4 + w;            // wave-uniform group 0..15
            const int idx = g * 64 + lane;       // 16B-chunk id, 0..1023
            const int r = idx >> 3, sc = idx & 7;
            const int dc = sc ^ (r & 7);         // fetch permuted chunk
            load_lds16(&A[(size_t)(m0 + r) * HID + k0 + dc * 8], As + g * 512);
            load_lds16(&B[(size_t)(n0 + r) * HID + k0 + dc * 8], Bs + g * 512);
        }
        __syncthreads();

        #pragma unroll
        for (int ks = 0; ks < 2; ++ks) {
            short8 af[4], bf[4];
            #pragma unroll
            for (int i = 0; i < 4; ++i) {
                const int ra = wm + i * 16 + c;
                const int rb = wn + i * 16 + c;
                af[i] = *(const short8*)
                    &As[ra * 64 + ((((ks << 2) + quad) ^ (c & 7)) << 3)];
                bf[i] = *(const short8*)
                    &Bs[rb * 64 + ((((ks << 2) + quad) ^ (c & 7)) << 3)];
            }
            #pragma unroll
            for (int i = 0; i < 4; ++i)
                #pragma unroll
                for (int j = 0; j < 4; ++j)
                    acc[i][j] = __builtin_amdgcn_mfma_f32_16x16x32_bf16(
                        af[i], bf[j], acc[i][j], 0, 0, 0);
        }
    }
}

// ---------------------------------------------------------------------------
// fp32 -> bf16 conversion: 12 segments of 1M elems (x = 8 segs, 4 weights)
// ---------------------------------------------------------------------------
__global__ __launch_bounds__(256) void cvt_bf16_kernel(
    const float* __restrict__ x,
    const float* __restrict__ wq, const float* __restrict__ wk,
    const float* __restrict__ wv, const float* __restrict__ wo,
    ushort_t* __restrict__ xb, ushort_t* __restrict__ wqb,
    ushort_t* __restrict__ wkb, ushort_t* __restrict__ wvb,
    ushort_t* __restrict__ wob)
{
    const int seg = blockIdx.y;
    const float* src; ushort_t* dst;
    if (seg < 8)       { src = x + (size_t)seg * 1048576; dst = xb + (size_t)seg * 1048576; }
    else if (seg == 8) { src = wq; dst = wqb; }
    else if (seg == 9) { src = wk; dst = wkb; }
    else if (seg == 10){ src = wv; dst = wvb; }
    else               { src = wo; dst = wob; }
    const int i = (blockIdx.x * 256 + threadIdx.x) * 8;
    const float4 a = *(const float4*)&src[i];
    const float4 b = *(const float4*)&src[i + 4];
    uint4 o;
    o.x = f2bf(a.x) | (f2bf(a.y) << 16);
    o.y = f2bf(a.z) | (f2bf(a.w) << 16);
    o.z = f2bf(b.x) | (f2bf(b.y) << 16);
    o.w = f2bf(b.z) | (f2bf(b.w) << 16);
    *(uint4*)&dst[i] = o;
}

// ---------------------------------------------------------------------------
// QKV projection. grid (8 n-tiles, 64 m-tiles, 3 weights); 128x128 tile.
// Q pre-scaled by 0.125*log2(e); K as (B,H,S,D); V^T as (B,H,D,S).
// ---------------------------------------------------------------------------
__global__ __launch_bounds__(256) void qkv_mfma_kernel(
    const ushort_t* __restrict__ xb,
    const ushort_t* __restrict__ wqb, const ushort_t* __restrict__ wkb,
    const ushort_t* __restrict__ wvb,
    const float* __restrict__ bq, const float* __restrict__ bk,
    const float* __restrict__ bv,
    ushort_t* __restrict__ qo, ushort_t* __restrict__ ko,
    ushort_t* __restrict__ vo)
{
    __shared__ __align__(16) ushort_t As[128 * 64];   // 16 KB
    __shared__ __align__(16) ushort_t Bs[128 * 64];   // 16 KB

    const int wsel = blockIdx.z;
    const ushort_t* W    = (wsel == 0) ? wqb : (wsel == 1) ? wkb : wvb;
    const float*    bias = (wsel == 0) ? bq  : (wsel == 1) ? bk  : bv;
    const int m0 = blockIdx.y * 128, n0 = blockIdx.x * 128;

    f32x4 acc[4][4];
    const f32x4 zero = {0.f, 0.f, 0.f, 0.f};
    #pragma unroll
    for (int i = 0; i < 4; ++i)
        #pragma unroll
        for (int j = 0; j < 4; ++j) acc[i][j] = zero;

    gemm_core_bk64(xb, W, m0, n0, As, Bs, acc);

    const int tid = threadIdx.x;
    const int w = tid >> 6, lane = tid & 63;
    const int wm = (w & 1) << 6, wn = (w >> 1) << 6;
    const int c = lane & 15, quad = lane >> 4;
    // 0.125 (1/sqrt(64)) * log2(e): scores land in log2 domain
    const float qscale = (wsel == 0) ? 0.18033688f : 1.0f;

    #pragma unroll
    for (int j = 0; j < 4; ++j) {
        const int n_g = n0 + wn + j * 16 + c;
        const float bj = bias[n_g];
        const int h = n_g >> 6, d = n_g & 63;
        #pragma unroll
        for (int i = 0; i < 4; ++i) {
            const int mbase = m0 + wm + i * 16 + quad * 4;
            const int b = mbase >> 11;
            const int sbase = mbase & (SL - 1);
            if (wsel == 2) {
                ushort4 pk;
                pk.x = (ushort_t)f2bf(acc[i][j][0] + bj);
                pk.y = (ushort_t)f2bf(acc[i][j][1] + bj);
                pk.z = (ushort_t)f2bf(acc[i][j][2] + bj);
                pk.w = (ushort_t)f2bf(acc[i][j][3] + bj);
                *(ushort4*)&vo[(((size_t)(b * NH + h) * HD) + d) * SL + sbase] = pk;
            } else {
                ushort_t* dst = (wsel == 0) ? qo : ko;
                #pragma unroll
                for (int reg = 0; reg < 4; ++reg) {
                    const float v = (acc[i][j][reg] + bj) * qscale;
                    dst[(((size_t)(b * NH + h) * SL) + sbase + reg) * HD + d] =
                        (ushort_t)f2bf(v);
                }
            }
        }
    }
}

// ---------------------------------------------------------------------------
// MFMA flash attention, fixed-base softmax, 128-row q-tiles, 32 rows/wave.
//
// v6 = v1 (the 98 us best-measured structure) + 16 KB swizzled Ps.
//
// Ladder so far: v1 98us (global_load_lds, 2 barriers/kt, 34 KB LDS,
// 4 blk/CU).  v2/v3/v4: register-prefetch T14 -> spills under every reg
// bound (accumulators hold the AGPR side; kr/vr+pf+qf don't fit the arch
// side) -> abandoned.  v5: LDS double-buffer 2-phase -> clean but 48 KB ->
// 3 blk/CU, occupancy 24.5% vs 35%, 107us -> TLP loss beats pipeline gain.
// Lesson: on this kernel wave-level TLP (m114 implicit overlap) is the
// latency-hiding mechanism that works; buy occupancy, not pipeline depth.
//
// v6 change vs v1: Ps pad-stride 72 (18 KB) -> XOR-swizzled stride 64
// (16 KB, verified correct in v2..v5).  LDS total = 8+8+16 = exactly 32 KB
// -> floor(160/32) = 5 blocks/CU (was 4).  __launch_bounds__(256,4) kept:
// it compiled this structure to 60 VGPR spill-free; the 2nd arg is a
// minimum, so at ~60 regs the HW schedules the 5th block the LDS permits.
// +25% resident waves dilute the per-iteration vmcnt(0)+barrier drain.
// ---------------------------------------------------------------------------
__global__ __launch_bounds__(256, 4) void attn_mfma_kernel(
    const ushort_t* __restrict__ q, const ushort_t* __restrict__ k,
    const ushort_t* __restrict__ vt, const int* __restrict__ mask,
    ushort_t* __restrict__ ao)
{
    __shared__ __align__(16) ushort_t Ks[64 * 64];    // 8 KB
    __shared__ __align__(16) ushort_t Vs[64 * 64];    // 8 KB
    __shared__ __align__(16) ushort_t Ps[128 * 64];   // 16 KB (swizzled)

    const int qt = blockIdx.x;    // 0..15
    const int bh = blockIdx.y;
    const int b = bh >> 4, h = bh & 15;
    const int tid = threadIdx.x;
    const int w = tid >> 6, lane = tid & 63;
    const int c = lane & 15, quad = lane >> 4;

    const ushort_t* qp = q  + (size_t)bh * SL * HD + (size_t)qt * 128 * HD;
    const ushort_t* kp = k  + (size_t)bh * SL * HD;
    const ushort_t* vp = vt + (size_t)bh * HD * SL;

    short8 qf[2][2];
    #pragma unroll
    for (int mi = 0; mi < 2; ++mi)
        #pragma unroll
        for (int ks = 0; ks < 2; ++ks)
            qf[mi][ks] = *(const short8*)&qp[(size_t)(w * 32 + mi * 16 + c) * HD
                                             + ks * 32 + quad * 8];

    float l_s[2][4] = {};
    f32x4 oa[2][4];
    const f32x4 zero = {0.f, 0.f, 0.f, 0.f};
    #pragma unroll
    for (int mi = 0; mi < 2; ++mi)
        #pragma unroll
        for (int ni = 0; ni < 4; ++ni) oa[mi][ni] = zero;

    for (int kt = 0; kt < SL / 64; ++kt) {
        __syncthreads();
        // K swizzle keyed (r>>2)&7 (QK^T reads row 4c+ni); V keyed r&7 (PV row ni*16+c)
        #pragma unroll
        for (int rd = 0; rd < 2; ++rd) {
            const int g = rd * 4 + w;
            const int t = g * 64 + lane;
            const int r = t >> 3, sc = t & 7;
            const int dck = sc ^ ((r >> 2) & 7);
            const int dcv = sc ^ (r & 7);
            load_lds16(&kp[(size_t)(kt * 64 + r) * HD + dck * 8], Ks + g * 512);
            load_lds16(&vp[(size_t)r * SL + kt * 64 + dcv * 8], Vs + g * 512);
        }
        __syncthreads();

        // S = Q @ K^T, log2 domain. Column c of tile ni = key 4c+ni.
        f32x4 sf[2][4];
        #pragma unroll
        for (int mi = 0; mi < 2; ++mi)
            #pragma unroll
            for (int ni = 0; ni < 4; ++ni) sf[mi][ni] = zero;
        #pragma unroll
        for (int ni = 0; ni < 4; ++ni) {
            const int krow = 4 * c + ni;
            #pragma unroll
            for (int ks = 0; ks < 2; ++ks) {
                const short8 kf = *(const short8*)
                    &Ks[krow * 64 + (((ks * 4 + quad) ^ (c & 7)) << 3)];
                #pragma unroll
                for (int mi = 0; mi < 2; ++mi)
                    sf[mi][ni] = __builtin_amdgcn_mfma_f32_16x16x32_bf16(
                        qf[mi][ks], kf, sf[mi][ni], 0, 0, 0);
            }
        }

        const int4 mzv = *(const int4*)&mask[b * SL + kt * 64 + 4 * c];
        const int mz[4] = {mzv.x, mzv.y, mzv.z, mzv.w};

        #pragma unroll
        for (int mi = 0; mi < 2; ++mi) {
            #pragma unroll
            for (int reg = 0; reg < 4; ++reg) {
                float p[4];
                #pragma unroll
                for (int ni = 0; ni < 4; ++ni) {
                    float pv = __builtin_amdgcn_exp2f(sf[mi][ni][reg]);
                    p[ni] = (mz[ni] == 0) ? 0.f : pv;
                }
                l_s[mi][reg] += (p[0] + p[1]) + (p[2] + p[3]);
                union { float f; uint_t u; } u0, u1, u2, u3;
                u0.f = p[0]; u1.f = p[1]; u2.f = p[2]; u3.f = p[3];
                uint2 pk;
                pk.x = __builtin_amdgcn_perm(u1.u, u0.u, 0x07060302u);
                pk.y = __builtin_amdgcn_perm(u3.u, u2.u, 0x07060302u);
                // P row quad*4+reg, cols 4c..4c+3 -> chunk c>>1, half c&1
                const int prow = w * 32 + mi * 16 + quad * 4 + reg;
                *(uint2*)&Ps[prow * 64 + (((c >> 1) ^ (prow & 7)) * 8)
                             + ((c & 1) * 4)] = pk;
            }
        }
        // wave-local LDS round-trip: no barrier needed

        short8 pf[2][2];
        #pragma unroll
        for (int mi = 0; mi < 2; ++mi)
            #pragma unroll
            for (int ks = 0; ks < 2; ++ks) {
                const int prow = w * 32 + mi * 16 + c;
                pf[mi][ks] = *(const short8*)
                    &Ps[prow * 64 + (((ks * 4 + quad) ^ (prow & 7)) << 3)];
            }
        #pragma unroll
        for (int ni = 0; ni < 4; ++ni) {
            const int n = ni * 16 + c;
            #pragma unroll
            for (int ks = 0; ks < 2; ++ks) {
                const short8 vf = *(const short8*)
                    &Vs[n * 64 + (((ks * 4 + quad) ^ (c & 7)) << 3)];
                #pragma unroll
                for (int mi = 0; mi < 2; ++mi)
                    oa[mi][ni] = __builtin_amdgcn_mfma_f32_16x16x32_bf16(
                        pf[mi][ks], vf, oa[mi][ni], 0, 0, 0);
            }
        }
    }

    #pragma unroll
    for (int mi = 0; mi < 2; ++mi) {
        #pragma unroll
        for (int reg = 0; reg < 4; ++reg) {
            float l = l_s[mi][reg];
            #pragma unroll
            for (int off = 1; off < 16; off <<= 1)
                l += __shfl_xor(l, off, 64);
            const float inv = 1.f / l;
            const int s_g = qt * 128 + w * 32 + mi * 16 + quad * 4 + reg;
            #pragma unroll
            for (int ni = 0; ni < 4; ++ni) {
                const int d = ni * 16 + c;
                ao[((size_t)(b * SL + s_g)) * HID + h * HD + d] =
                    (ushort_t)f2bf(oa[mi][ni][reg] * inv);
            }
        }
    }
}

// ---------------------------------------------------------------------------
// Output projection: out(fp32) = ao_bf @ Wo^T + bo. grid (8, 64).
// ---------------------------------------------------------------------------
__global__ __launch_bounds__(256) void out_mfma_kernel(
    const ushort_t* __restrict__ aob, const ushort_t* __restrict__ wob,
    const float* __restrict__ bo, float* __restrict__ out)
{
    __shared__ __align__(16) ushort_t As[128 * 64];
    __shared__ __align__(16) ushort_t Bs[128 * 64];

    const int m0 = blockIdx.y * 128, n0 = blockIdx.x * 128;

    f32x4 acc[4][4];
    const f32x4 zero = {0.f, 0.f, 0.f, 0.f};
    #pragma unroll
    for (int i = 0; i < 4; ++i)
        #pragma unroll
        for (int j = 0; j < 4; ++j) acc[i][j] = zero;

    gemm_core_bk64(aob, wob, m0, n0, As, Bs, acc);

    const int tid = threadIdx.x;
    const int w = tid >> 6, lane = tid & 63;
    const int wm = (w & 1) << 6, wn = (w >> 1) << 6;
    const int c = lane & 15, quad = lane >> 4;

    #pragma unroll
    for (int j = 0; j < 4; ++j) {
        const int n_g = n0 + wn + j * 16 + c;
        const float bj = bo[n_g];
        #pragma unroll
        for (int i = 0; i < 4; ++i) {
            const int mbase = m0 + wm + i * 16 + quad * 4;
            #pragma unroll
            for (int reg = 0; reg < 4; ++reg)
                out[(size_t)(mbase + reg) * HID + n_g] = acc[i][j][reg] + bj;
        }
    }
}

extern "C" void kernel_launch(void* const* d_in, const int* in_sizes, int n_in,
                              void* d_out, int out_size, void* d_ws, size_t ws_size,
                              hipStream_t stream)
{
    const float* x    = (const float*)d_in[0];
    const int*   mask = (const int*)d_in[1];
    const float* Wq   = (const float*)d_in[2];
    const float* bq   = (const float*)d_in[3];
    const float* Wk   = (const float*)d_in[4];
    const float* bk   = (const float*)d_in[5];
    const float* Wv   = (const float*)d_in[6];
    const float* bv   = (const float*)d_in[7];
    const float* Wo   = (const float*)d_in[8];
    const float* bo   = (const float*)d_in[9];
    float* out = (float*)d_out;

    ushort_t* p = (ushort_t*)d_ws;
    ushort_t* xb  = p; p += (size_t)MROWS * HID;
    ushort_t* wqb = p; p += (size_t)HID * HID;
    ushort_t* wkb = p; p += (size_t)HID * HID;
    ushort_t* wvb = p; p += (size_t)HID * HID;
    ushort_t* wob = p; p += (size_t)HID * HID;
    ushort_t* qb  = p; p += (size_t)MROWS * HID;
    ushort_t* kb  = p; p += (size_t)MROWS * HID;
    ushort_t* vtb = p; p += (size_t)MROWS * HID;
    ushort_t* aob = p; p += (size_t)MROWS * HID;

    cvt_bf16_kernel<<<dim3(512, 12), 256, 0, stream>>>(
        x, Wq, Wk, Wv, Wo, xb, wqb, wkb, wvb, wob);
    qkv_mfma_kernel<<<dim3(8, 64, 3), 256, 0, stream>>>(
        xb, wqb, wkb, wvb, bq, bk, bv, qb, kb, vtb);
    attn_mfma_kernel<<<dim3(16, 64), 256, 0, stream>>>(
        qb, kb, vtb, mask, aob);
    out_mfma_kernel<<<dim3(8, 64), 256, 0, stream>>>(
        aob, wob, bo, out);
}